// Round 16
// baseline (135.243 us; speedup 1.0000x reference)
//
#include <hip/hip_runtime.h>
#include <hip/hip_bf16.h>
#include <stdint.h>

#define T_SEQ 4096
#define NH 12

#if __has_builtin(__builtin_amdgcn_exp2f)
#define EXP2F __builtin_amdgcn_exp2f
#else
#define EXP2F exp2f
#endif

typedef __attribute__((ext_vector_type(4))) float f32x4;
typedef __attribute__((ext_vector_type(8))) __bf16 bf16x8;

__device__ inline ushort f2b(float f) {
  __hip_bfloat16 h = __float2bfloat16(f);
  return *reinterpret_cast<ushort*>(&h);
}
__device__ inline float b2f(ushort u) {
  union { uint i; float f; } v; v.i = (uint)u << 16; return v.f;
}

__device__ inline void gload_lds16(const void* g, void* lds) {
  auto g1 = (const __attribute__((address_space(1))) uint32_t*)(uintptr_t)g;
  auto l3 = (__attribute__((address_space(3))) uint32_t*)(uintptr_t)lds;
  __builtin_amdgcn_global_load_lds(g1, l3, 16, 0, 0);
}

// ---------------- fused prep: 3x fp32->bf16 convert + RoPE tables, one launch ----------------
__global__ __launch_bounds__(256) void prep_all(const float* __restrict__ x,
                                                const float* __restrict__ wA,
                                                const float* __restrict__ wP,
                                                ushort* __restrict__ xb,
                                                ushort* __restrict__ wAb,
                                                ushort* __restrict__ wPb,
                                                float* __restrict__ cosT,
                                                float* __restrict__ sinT) {
  const int u = blockIdx.x * blockDim.x + threadIdx.x;
  if (u < 688128) {
    const float* src;
    ushort* dst;
    long i;
    if (u < 393216)      { src = x;  dst = xb;  i = u; }
    else if (u < 614400) { src = wA; dst = wAb; i = u - 393216; }
    else                 { src = wP; dst = wPb; i = u - 614400; }
    const float4* s4 = (const float4*)src;
    float4 a = s4[i * 2], b = s4[i * 2 + 1];
    uint4 o;
    o.x = (uint)f2b(a.x) | ((uint)f2b(a.y) << 16);
    o.y = (uint)f2b(a.z) | ((uint)f2b(a.w) << 16);
    o.z = (uint)f2b(b.x) | ((uint)f2b(b.y) << 16);
    o.w = (uint)f2b(b.z) | ((uint)f2b(b.w) << 16);
    *(uint4*)(dst + i * 8) = o;
  } else if (u < 704512) {
    const int base = (u - 688128) * 8;   // i = t*32 + d
    const int t = base >> 5;
#pragma unroll
    for (int j = 0; j < 8; ++j) {
      const int d = (base + j) & 31;
      float theta = 1.0f / powf(10000.0f, (float)d * (1.0f / 32.0f));
      float a = (float)t * theta;
      cosT[base + j] = cosf(a);
      sinT[base + j] = sinf(a);
    }
  }
}

// ---------------- GEMM1 + fused RoPE/reorder epilogue (1D grid, XCD-swizzled) ----------------
__global__ __launch_bounds__(256) void gemm_qkv(const ushort* __restrict__ A,
                                                const ushort* __restrict__ B,
                                                const float* __restrict__ cosT,
                                                const float* __restrict__ sinT,
                                                ushort* __restrict__ Q,
                                                ushort* __restrict__ Kb,
                                                ushort* __restrict__ Vt) {
  __shared__ ushort As[128 * 64];
  __shared__ ushort Bs[128 * 64];
  const int wg = (blockIdx.x & 7) * 72 + (blockIdx.x >> 3);
  const int bx = wg % 18;
  const int by = wg / 18;
  const int t = threadIdx.x;
  const int w = t >> 6, l = t & 63;
  const int lo = l & 15, hi = l >> 4;
  const int wr = w >> 1, wc = w & 1;
  const long arow = (long)by * 128;
  const long brow = (long)bx * 128;
  const int K = 768;
  f32x4 acc[4][4] = {};
  for (int k0 = 0; k0 < K; k0 += 64) {
    for (int i = 0; i < 4; ++i) {
      int e = i * 2048 + t * 8;
      int r = e >> 6, c = e & 63;
      const ushort* ga = A + (arow + r) * (long)K + k0 + c;
      const ushort* gb = B + (brow + r) * (long)K + k0 + c;
      uint32_t ldsoff = i * 4096 + w * 1024;
      gload_lds16(ga, (char*)As + ldsoff);
      gload_lds16(gb, (char*)Bs + ldsoff);
    }
    __syncthreads();
    for (int kk = 0; kk < 2; ++kk) {
      bf16x8 af[4], bfr[4];
      for (int m = 0; m < 4; ++m)
        af[m] = *(const bf16x8*)&As[(wr * 64 + m * 16 + lo) * 64 + kk * 32 + hi * 8];
      for (int n = 0; n < 4; ++n)
        bfr[n] = *(const bf16x8*)&Bs[(wc * 64 + n * 16 + lo) * 64 + kk * 32 + hi * 8];
      for (int m = 0; m < 4; ++m)
        for (int n = 0; n < 4; ++n)
          acc[m][n] = __builtin_amdgcn_mfma_f32_16x16x32_bf16(af[m], bfr[n], acc[m][n], 0, 0, 0);
    }
    __syncthreads();
  }
  // ---- fused epilogue ----
  const int rq = bx / 6;                 // 0=Q, 1=K, 2=V
  const int h  = (bx % 6) * 2 + wc;      // head for this thread's cols
  const long hT = (long)h * T_SEQ;
  if (rq < 2) {
    ushort* dst = (rq == 0) ? Q : Kb;
    const float qsc = (rq == 0) ? 0.125f * 1.44269504f : 1.0f;
#pragma unroll
    for (int m = 0; m < 4; ++m)
#pragma unroll
      for (int r = 0; r < 4; ++r) {
        const long trow = arow + wr * 64 + m * 16 + hi * 4 + r;
        ushort* rowp = dst + (hT + trow) * 64;
        const float* cp = cosT + trow * 32;
        const float* sp = sinT + trow * 32;
#pragma unroll
        for (int n = 0; n < 2; ++n) {
          const int dd = n * 16 + lo;
          const float cs = cp[dd], sn = sp[dd];
          const float a = acc[m][n][r], b = acc[m][n + 2][r];
          rowp[dd]      = f2b((a * cs - b * sn) * qsc);
          rowp[dd + 32] = f2b((a * sn + b * cs) * qsc);
        }
      }
  } else {
#pragma unroll
    for (int m = 0; m < 4; ++m) {
      const long trow0 = arow + wr * 64 + m * 16 + hi * 4;
#pragma unroll
      for (int n = 0; n < 4; ++n) {
        const int d = n * 16 + lo;
        uint2 pk;
        pk.x = (uint)f2b(acc[m][n][0]) | ((uint)f2b(acc[m][n][1]) << 16);
        pk.y = (uint)f2b(acc[m][n][2]) | ((uint)f2b(acc[m][n][3]) << 16);
        *(uint2*)(Vt + ((long)h * 64 + d) * T_SEQ + trow0) = pk;
      }
    }
  }
}

// ---------------- bf16 GEMM, C = A * B^T (fp32 out; out-proj; 1D grid, XCD-swizzled) ----------------
__global__ __launch_bounds__(256) void gemm_bt(const ushort* __restrict__ A,
                                               const ushort* __restrict__ B,
                                               float* __restrict__ C,
                                               int M, int N, int K) {
  __shared__ ushort As[128 * 64];
  __shared__ ushort Bs[128 * 64];
  const int nbx = N >> 7;
  const int nwg = (M >> 7) * nbx;
  const int cpx = nwg >> 3;
  const int wg = (blockIdx.x & 7) * cpx + (blockIdx.x >> 3);
  const int bx = wg % nbx;
  const int by = wg / nbx;
  const int t = threadIdx.x;
  const int w = t >> 6, l = t & 63;
  const int lo = l & 15, hi = l >> 4;
  const int wr = w >> 1, wc = w & 1;
  const long arow = (long)by * 128;
  const long brow = (long)bx * 128;
  f32x4 acc[4][4] = {};
  for (int k0 = 0; k0 < K; k0 += 64) {
    for (int i = 0; i < 4; ++i) {
      int e = i * 2048 + t * 8;
      int r = e >> 6, c = e & 63;
      const ushort* ga = A + (arow + r) * (long)K + k0 + c;
      const ushort* gb = B + (brow + r) * (long)K + k0 + c;
      uint32_t ldsoff = i * 4096 + w * 1024;
      gload_lds16(ga, (char*)As + ldsoff);
      gload_lds16(gb, (char*)Bs + ldsoff);
    }
    __syncthreads();
    for (int kk = 0; kk < 2; ++kk) {
      bf16x8 af[4], bfr[4];
      for (int m = 0; m < 4; ++m)
        af[m] = *(const bf16x8*)&As[(wr * 64 + m * 16 + lo) * 64 + kk * 32 + hi * 8];
      for (int n = 0; n < 4; ++n)
        bfr[n] = *(const bf16x8*)&Bs[(wc * 64 + n * 16 + lo) * 64 + kk * 32 + hi * 8];
      for (int m = 0; m < 4; ++m)
        for (int n = 0; n < 4; ++n)
          acc[m][n] = __builtin_amdgcn_mfma_f32_16x16x32_bf16(af[m], bfr[n], acc[m][n], 0, 0, 0);
    }
    __syncthreads();
  }
  for (int m = 0; m < 4; ++m) {
    long row0 = arow + wr * 64 + m * 16 + hi * 4;
    for (int n = 0; n < 4; ++n) {
      long col = brow + wc * 64 + n * 16 + lo;
      for (int r = 0; r < 4; ++r)
        C[(row0 + r) * (long)N + col] = acc[m][n][r];
    }
  }
}

// ---------------- flash attention: 8-wave blocks, EQUAL 512-key chunks, permuted-K, no P-LDS ----------------
// 1728 blocks (1.7 generations at 4 blocks/CU => real backfill), lengths 2-8 iters (was 2-16):
// fixes the co-residency tail (r15: all-resident => dispatch order irrelevant; length variance
// was the occupancy killer). Unit = (head, qb-parity): 24 units x 72 blocks, 3 units/XCD
// (1536-1632 iters each, +-3%), K/V L2 locality kept. Partials: compact prefix layout,
// g=qb>>2, slot = h*1152 + 16g(g+1) + r(g+1) + cc, r = 8(qb&3)+w; 30.1MB.
// K rows staged PERMUTED (pi) so each lane's softmax outputs ARE its PV A-fragment.
// Causal key: k0 + (kt>>1)*32 + (kt&1)*4 + hi*8 + r.
__global__ __launch_bounds__(512, 4) void flash_attn(const ushort* __restrict__ Q,
                                                     const ushort* __restrict__ Kb,
                                                     const ushort* __restrict__ Vt,
                                                     char* __restrict__ part) {
  const int n    = blockIdx.x;
  const int slot = n >> 3;
  const int u    = slot / 72;                       // unit slot within XCD (0..2)
  int b          = slot - u * 72;                   // block index within unit
  const int unit = (n & 7) * 3 + u;                 // 0..23
  const int h    = unit >> 1;
  const int par  = unit & 1;
  const int top  = par ? 31 : 30;
  int qb = 0, cc = 0;
#pragma unroll 1
  for (int j = 0; j < 16; ++j) {                    // decode b -> (qb, cc), longest-qb first
    int q = top - 2 * j;
    int nc = (q >> 2) + 1;
    if (b < nc) { qb = q; cc = b; break; }
    b -= nc;
  }
  const int kstart  = cc << 9;
  const int blk_lim = qb * 128 + 128;
  const int kend = (kstart + 512 < blk_lim) ? kstart + 512 : blk_lim;

  __shared__ ushort Ks[2][4096];   // [64 rows][64 bf16], rows key-permuted, chunks XOR-swizzled
  __shared__ ushort Vs[2][4096];

  const int t = threadIdx.x;
  const int w = t >> 6, l = t & 63;
  const int lo = l & 15, hi = l >> 4, lo7 = l & 7;
  const int qrow0 = qb * 128 + w * 16;
  const int qlim  = qrow0 + 16;
  const int qabs  = qrow0 + lo;
  const long hT   = (long)h * T_SEQ;
  const long hT64 = (long)h * 64;

  const int srow8 = l >> 3;               // 0..7: row within this wave's 8-row group
  const int row_w = w * 8 + srow8;        // 0..63: LDS tile row this lane stages
  const int prow  = ((row_w >> 5) & 1) * 32 + ((row_w >> 2) & 3) * 8 +
                    ((row_w >> 4) & 1) * 4 + (row_w & 3);   // pi(row_w): source K key
  const int schk  = (l & 7) ^ srow8;      // inverse-swizzled source 16B-chunk

  bf16x8 qf0, qf1;
  {
    const ushort* qp = Q + (hT + qrow0 + lo) * 64 + hi * 8;
    qf0 = *(const bf16x8*)qp;
    qf1 = *(const bf16x8*)(qp + 32);
  }
  f32x4 o[4] = {};
  float m = -1e30f, lsum = 0.0f;

#define STAGE(buf, k0s)                                                         \
  {                                                                             \
    gload_lds16(Kb + (hT + (k0s) + prow) * 64 + schk * 8,                       \
                (char*)&Ks[buf][0] + w * 1024);                                 \
    gload_lds16(Vt + (hT64 + row_w) * T_SEQ + (k0s) + schk * 8,                 \
                (char*)&Vs[buf][0] + w * 1024);                                 \
  }

  STAGE(0, kstart);
  __syncthreads();
  int buf = 0;

  for (int k0 = kstart; k0 < kend; k0 += 64) {
    if (k0 + 64 < kend) STAGE(buf ^ 1, k0 + 64);
    if (k0 < qlim) {
      const ushort* kt_ = &Ks[buf][0];
      const ushort* vt_ = &Vs[buf][0];
      // --- S^T = K . Q^T from swizzled LDS (rows key-permuted) ---
      f32x4 s[4];
      __builtin_amdgcn_s_setprio(1);
#pragma unroll
      for (int kt = 0; kt < 4; ++kt) {
        int rr = kt * 16 + lo;
        bf16x8 ka = *(const bf16x8*)(kt_ + rr * 64 + ((hi ^ lo7) * 8));
        bf16x8 kc = *(const bf16x8*)(kt_ + rr * 64 + (((4 + hi) ^ lo7) * 8));
        f32x4 a = {};
        a = __builtin_amdgcn_mfma_f32_16x16x32_bf16(ka, qf0, a, 0, 0, 0);
        a = __builtin_amdgcn_mfma_f32_16x16x32_bf16(kc, qf1, a, 0, 0, 0);
        s[kt] = a;
      }
      __builtin_amdgcn_s_setprio(0);
      // --- V fragments early (latency overlaps softmax) ---
      bf16x8 vf[8];
#pragma unroll
      for (int dt = 0; dt < 4; ++dt)
#pragma unroll
        for (int cv = 0; cv < 2; ++cv) {
          int rr = dt * 16 + lo;
          vf[dt * 2 + cv] = *(const bf16x8*)(vt_ + rr * 64 + (((cv * 4 + hi) ^ lo7) * 8));
        }
      // --- causal mask (diagonal tiles only); key honors the row permutation ---
      if (k0 + 64 > qrow0) {
#pragma unroll
        for (int kt = 0; kt < 4; ++kt) {
          const int bkt = (kt >> 1) * 32 + (kt & 1) * 4;
#pragma unroll
          for (int r = 0; r < 4; ++r) {
            int key = k0 + bkt + hi * 8 + r;
            if (key > qabs) s[kt][r] = -1e30f;
          }
        }
      }
      // --- row max: 15 in-lane fmax + 2 shfl ---
      float mt = s[0][0];
#pragma unroll
      for (int kt = 0; kt < 4; ++kt)
#pragma unroll
        for (int r = 0; r < 4; ++r) mt = fmaxf(mt, s[kt][r]);
      mt = fmaxf(mt, __shfl_xor(mt, 16));
      mt = fmaxf(mt, __shfl_xor(mt, 32));
      // --- defer-max rescale (THR=8 in log2 domain) ---
      if (!__all(mt - m <= 8.0f)) {
        float mn = fmaxf(m, mt);
        float alpha = EXP2F(m - mn);
        m = mn;
        lsum *= alpha;
#pragma unroll
        for (int r = 0; r < 4; ++r) {
          float ar = __shfl(alpha, hi * 4 + r);
#pragma unroll
          for (int dt = 0; dt < 4; ++dt) o[dt][r] *= ar;
        }
      }
      // --- exp2 + per-lane sum + pack P into registers (no LDS!) ---
      uint us[8];
#pragma unroll
      for (int kt = 0; kt < 4; ++kt) {
        float p0 = EXP2F(s[kt][0] - m);
        float p1 = EXP2F(s[kt][1] - m);
        float p2 = EXP2F(s[kt][2] - m);
        float p3 = EXP2F(s[kt][3] - m);
        lsum += (p0 + p1) + (p2 + p3);
        us[kt * 2]     = (uint)f2b(p0) | ((uint)f2b(p1) << 16);
        us[kt * 2 + 1] = (uint)f2b(p2) | ((uint)f2b(p3) << 16);
      }
      // --- PV: A-fragment is a pure register reassembly ---
      __builtin_amdgcn_s_setprio(1);
#pragma unroll
      for (int cv = 0; cv < 2; ++cv) {
        union { uint4 q; bf16x8 v; } pc;
        pc.q.x = us[cv * 4 + 0];
        pc.q.y = us[cv * 4 + 1];
        pc.q.z = us[cv * 4 + 2];
        pc.q.w = us[cv * 4 + 3];
#pragma unroll
        for (int dt = 0; dt < 4; ++dt)
          o[dt] = __builtin_amdgcn_mfma_f32_16x16x32_bf16(pc.v, vf[dt * 2 + cv], o[dt], 0, 0, 0);
      }
      __builtin_amdgcn_s_setprio(0);
    }
    __syncthreads();
    buf ^= 1;
  }
#undef STAGE

  // --- write partial (unnormalized); compact prefix-indexed slot ---
  if (kstart < qlim) {
    lsum += __shfl_xor(lsum, 16);
    lsum += __shfl_xor(lsum, 32);
    const int g  = qb >> 2;
    const int rr = 8 * (qb & 3) + w;
    const long slotp = (long)h * 1152 + 16 * g * (g + 1) + rr * (g + 1) + cc;
    char* pb = part + slotp * 2176;
    ushort* po = (ushort*)pb;
#pragma unroll
    for (int dt = 0; dt < 4; ++dt)
#pragma unroll
      for (int r = 0; r < 4; ++r)
        po[(hi * 4 + r) * 64 + dt * 16 + lo] = f2b(o[dt][r]);
    if (hi == 0) {
      ((float*)(pb + 2048))[lo] = m;
      ((float*)(pb + 2112))[lo] = lsum;
    }
  }
}

// ---------------- split-K combine (compact prefix-indexed partials, nch = qg/32 + 1) ----------------
__global__ __launch_bounds__(64) void flash_combine(const char* __restrict__ part,
                                                    ushort* __restrict__ Y) {
  const int qg = blockIdx.x, h = blockIdx.y, d = threadIdx.x;
  const int qrow0 = qg * 16;
  const int g = qg >> 5, rr = qg & 31;
  const int nch = g + 1;
  const char* ub = part + ((long)h * 1152 + 16 * g * (g + 1) + (long)rr * (g + 1)) * 2176;
  float Mg[16];
#pragma unroll
  for (int r = 0; r < 16; ++r) Mg[r] = -1e30f;
  for (int cc = 0; cc < nch; ++cc) {
    const float* mp = (const float*)(ub + cc * 2176 + 2048);
#pragma unroll
    for (int r = 0; r < 16; ++r) Mg[r] = fmaxf(Mg[r], mp[r]);
  }
  float acc[16], lg[16];
#pragma unroll
  for (int r = 0; r < 16; ++r) { acc[r] = 0.0f; lg[r] = 0.0f; }
  for (int cc = 0; cc < nch; ++cc) {
    const ushort* op = (const ushort*)(ub + cc * 2176);
    const float* mp = (const float*)(ub + cc * 2176 + 2048);
    const float* lp = (const float*)(ub + cc * 2176 + 2112);
#pragma unroll
    for (int r = 0; r < 16; ++r) {
      float wgt = EXP2F(mp[r] - Mg[r]);
      acc[r] += wgt * b2f(op[r * 64 + d]);
      lg[r]  += wgt * lp[r];
    }
  }
#pragma unroll
  for (int r = 0; r < 16; ++r)
    Y[(long)(qrow0 + r) * 768 + h * 64 + d] = f2b(acc[r] / lg[r]);
}

extern "C" void kernel_launch(void* const* d_in, const int* in_sizes, int n_in,
                              void* d_out, int out_size, void* d_ws, size_t ws_size,
                              hipStream_t stream) {
  const float* x      = (const float*)d_in[0];
  const float* w_attn = (const float*)d_in[1];
  const float* w_proj = (const float*)d_in[2];
  float* out = (float*)d_out;
  char* ws = (char*)d_ws;

  ushort* xb   = (ushort*)(ws);                 // 4096*768
  ushort* wAb  = (ushort*)(ws + 6291456);       // 2304*768
  ushort* wPb  = (ushort*)(ws + 9830400);       // 768*768
  float*  cosT = (float*)(ws + 11010048);       // 4096*32
  float*  sinT = (float*)(ws + 11534336);
  char*   partR = (ws + 12058624);              // flash split-K partials (compact, 30.1MB)
  ushort* Qb   = (ushort*)(ws + 49807360);      // [12][4096][64]
  ushort* Kbb  = (ushort*)(ws + 56098816);
  ushort* Vt   = (ushort*)(ws + 62390272);      // [12][64][4096]
  ushort* Yb   = (ushort*)(ws + 68681728);      // [4096][768]

  prep_all<<<2752, 256, 0, stream>>>(x, w_attn, w_proj, xb, wAb, wPb, cosT, sinT);
  gemm_qkv<<<576, 256, 0, stream>>>(xb, wAb, cosT, sinT, Qb, Kbb, Vt);
  flash_attn<<<1728, 512, 0, stream>>>(Qb, Kbb, Vt, partR);
  flash_combine<<<dim3(256, NH), 64, 0, stream>>>(partR, Yb);
  gemm_bt<<<192, 256, 0, stream>>>(Yb, wPb, out, 4096, 768, 768);
}

// Round 17
// 125.992 us; speedup vs baseline: 1.0734x; 1.0734x over previous
//
#include <hip/hip_runtime.h>
#include <hip/hip_bf16.h>
#include <stdint.h>

#define T_SEQ 4096
#define NH 12

#if __has_builtin(__builtin_amdgcn_exp2f)
#define EXP2F __builtin_amdgcn_exp2f
#else
#define EXP2F exp2f
#endif

typedef __attribute__((ext_vector_type(4))) float f32x4;
typedef __attribute__((ext_vector_type(8))) __bf16 bf16x8;

__device__ inline ushort f2b(float f) {
  __hip_bfloat16 h = __float2bfloat16(f);
  return *reinterpret_cast<ushort*>(&h);
}
__device__ inline float b2f(ushort u) {
  union { uint i; float f; } v; v.i = (uint)u << 16; return v.f;
}
// one-instruction packed f32x2 -> bf16x2 (RNE); ~8x fewer VALU ops than 2x f2b+merge
__device__ inline uint cvt_pk_bf16(float a, float b) {
  uint r;
  asm("v_cvt_pk_bf16_f32 %0, %1, %2" : "=v"(r) : "v"(a), "v"(b));
  return r;
}

__device__ inline void gload_lds16(const void* g, void* lds) {
  auto g1 = (const __attribute__((address_space(1))) uint32_t*)(uintptr_t)g;
  auto l3 = (__attribute__((address_space(3))) uint32_t*)(uintptr_t)lds;
  __builtin_amdgcn_global_load_lds(g1, l3, 16, 0, 0);
}

// ---------------- fused prep: 3x fp32->bf16 convert + RoPE tables, one launch ----------------
__global__ __launch_bounds__(256) void prep_all(const float* __restrict__ x,
                                                const float* __restrict__ wA,
                                                const float* __restrict__ wP,
                                                ushort* __restrict__ xb,
                                                ushort* __restrict__ wAb,
                                                ushort* __restrict__ wPb,
                                                float* __restrict__ cosT,
                                                float* __restrict__ sinT) {
  const int u = blockIdx.x * blockDim.x + threadIdx.x;
  if (u < 688128) {
    const float* src;
    ushort* dst;
    long i;
    if (u < 393216)      { src = x;  dst = xb;  i = u; }
    else if (u < 614400) { src = wA; dst = wAb; i = u - 393216; }
    else                 { src = wP; dst = wPb; i = u - 614400; }
    const float4* s4 = (const float4*)src;
    float4 a = s4[i * 2], b = s4[i * 2 + 1];
    uint4 o;
    o.x = (uint)f2b(a.x) | ((uint)f2b(a.y) << 16);
    o.y = (uint)f2b(a.z) | ((uint)f2b(a.w) << 16);
    o.z = (uint)f2b(b.x) | ((uint)f2b(b.y) << 16);
    o.w = (uint)f2b(b.z) | ((uint)f2b(b.w) << 16);
    *(uint4*)(dst + i * 8) = o;
  } else if (u < 704512) {
    const int base = (u - 688128) * 8;   // i = t*32 + d
    const int t = base >> 5;
#pragma unroll
    for (int j = 0; j < 8; ++j) {
      const int d = (base + j) & 31;
      float theta = 1.0f / powf(10000.0f, (float)d * (1.0f / 32.0f));
      float a = (float)t * theta;
      cosT[base + j] = cosf(a);
      sinT[base + j] = sinf(a);
    }
  }
}

// ---------------- GEMM1 + fused RoPE/reorder epilogue (1D grid, XCD-swizzled) ----------------
__global__ __launch_bounds__(256) void gemm_qkv(const ushort* __restrict__ A,
                                                const ushort* __restrict__ B,
                                                const float* __restrict__ cosT,
                                                const float* __restrict__ sinT,
                                                ushort* __restrict__ Q,
                                                ushort* __restrict__ Kb,
                                                ushort* __restrict__ Vt) {
  __shared__ ushort As[128 * 64];
  __shared__ ushort Bs[128 * 64];
  const int wg = (blockIdx.x & 7) * 72 + (blockIdx.x >> 3);
  const int bx = wg % 18;
  const int by = wg / 18;
  const int t = threadIdx.x;
  const int w = t >> 6, l = t & 63;
  const int lo = l & 15, hi = l >> 4;
  const int wr = w >> 1, wc = w & 1;
  const long arow = (long)by * 128;
  const long brow = (long)bx * 128;
  const int K = 768;
  f32x4 acc[4][4] = {};
  for (int k0 = 0; k0 < K; k0 += 64) {
    for (int i = 0; i < 4; ++i) {
      int e = i * 2048 + t * 8;
      int r = e >> 6, c = e & 63;
      const ushort* ga = A + (arow + r) * (long)K + k0 + c;
      const ushort* gb = B + (brow + r) * (long)K + k0 + c;
      uint32_t ldsoff = i * 4096 + w * 1024;
      gload_lds16(ga, (char*)As + ldsoff);
      gload_lds16(gb, (char*)Bs + ldsoff);
    }
    __syncthreads();
    for (int kk = 0; kk < 2; ++kk) {
      bf16x8 af[4], bfr[4];
      for (int m = 0; m < 4; ++m)
        af[m] = *(const bf16x8*)&As[(wr * 64 + m * 16 + lo) * 64 + kk * 32 + hi * 8];
      for (int n = 0; n < 4; ++n)
        bfr[n] = *(const bf16x8*)&Bs[(wc * 64 + n * 16 + lo) * 64 + kk * 32 + hi * 8];
      for (int m = 0; m < 4; ++m)
        for (int n = 0; n < 4; ++n)
          acc[m][n] = __builtin_amdgcn_mfma_f32_16x16x32_bf16(af[m], bfr[n], acc[m][n], 0, 0, 0);
    }
    __syncthreads();
  }
  // ---- fused epilogue ----
  const int rq = bx / 6;                 // 0=Q, 1=K, 2=V
  const int h  = (bx % 6) * 2 + wc;      // head for this thread's cols
  const long hT = (long)h * T_SEQ;
  if (rq < 2) {
    ushort* dst = (rq == 0) ? Q : Kb;
    const float qsc = (rq == 0) ? 0.125f * 1.44269504f : 1.0f;
#pragma unroll
    for (int m = 0; m < 4; ++m)
#pragma unroll
      for (int r = 0; r < 4; ++r) {
        const long trow = arow + wr * 64 + m * 16 + hi * 4 + r;
        ushort* rowp = dst + (hT + trow) * 64;
        const float* cp = cosT + trow * 32;
        const float* sp = sinT + trow * 32;
#pragma unroll
        for (int n = 0; n < 2; ++n) {
          const int dd = n * 16 + lo;
          const float cs = cp[dd], sn = sp[dd];
          const float a = acc[m][n][r], b = acc[m][n + 2][r];
          rowp[dd]      = f2b((a * cs - b * sn) * qsc);
          rowp[dd + 32] = f2b((a * sn + b * cs) * qsc);
        }
      }
  } else {
#pragma unroll
    for (int m = 0; m < 4; ++m) {
      const long trow0 = arow + wr * 64 + m * 16 + hi * 4;
#pragma unroll
      for (int n = 0; n < 4; ++n) {
        const int d = n * 16 + lo;
        uint2 pk;
        pk.x = (uint)f2b(acc[m][n][0]) | ((uint)f2b(acc[m][n][1]) << 16);
        pk.y = (uint)f2b(acc[m][n][2]) | ((uint)f2b(acc[m][n][3]) << 16);
        *(uint2*)(Vt + ((long)h * 64 + d) * T_SEQ + trow0) = pk;
      }
    }
  }
}

// ---------------- bf16 GEMM, C = A * B^T (fp32 out; out-proj; 1D grid, XCD-swizzled) ----------------
__global__ __launch_bounds__(256) void gemm_bt(const ushort* __restrict__ A,
                                               const ushort* __restrict__ B,
                                               float* __restrict__ C,
                                               int M, int N, int K) {
  __shared__ ushort As[128 * 64];
  __shared__ ushort Bs[128 * 64];
  const int nbx = N >> 7;
  const int nwg = (M >> 7) * nbx;
  const int cpx = nwg >> 3;
  const int wg = (blockIdx.x & 7) * cpx + (blockIdx.x >> 3);
  const int bx = wg % nbx;
  const int by = wg / nbx;
  const int t = threadIdx.x;
  const int w = t >> 6, l = t & 63;
  const int lo = l & 15, hi = l >> 4;
  const int wr = w >> 1, wc = w & 1;
  const long arow = (long)by * 128;
  const long brow = (long)bx * 128;
  f32x4 acc[4][4] = {};
  for (int k0 = 0; k0 < K; k0 += 64) {
    for (int i = 0; i < 4; ++i) {
      int e = i * 2048 + t * 8;
      int r = e >> 6, c = e & 63;
      const ushort* ga = A + (arow + r) * (long)K + k0 + c;
      const ushort* gb = B + (brow + r) * (long)K + k0 + c;
      uint32_t ldsoff = i * 4096 + w * 1024;
      gload_lds16(ga, (char*)As + ldsoff);
      gload_lds16(gb, (char*)Bs + ldsoff);
    }
    __syncthreads();
    for (int kk = 0; kk < 2; ++kk) {
      bf16x8 af[4], bfr[4];
      for (int m = 0; m < 4; ++m)
        af[m] = *(const bf16x8*)&As[(wr * 64 + m * 16 + lo) * 64 + kk * 32 + hi * 8];
      for (int n = 0; n < 4; ++n)
        bfr[n] = *(const bf16x8*)&Bs[(wc * 64 + n * 16 + lo) * 64 + kk * 32 + hi * 8];
      for (int m = 0; m < 4; ++m)
        for (int n = 0; n < 4; ++n)
          acc[m][n] = __builtin_amdgcn_mfma_f32_16x16x32_bf16(af[m], bfr[n], acc[m][n], 0, 0, 0);
    }
    __syncthreads();
  }
  for (int m = 0; m < 4; ++m) {
    long row0 = arow + wr * 64 + m * 16 + hi * 4;
    for (int n = 0; n < 4; ++n) {
      long col = brow + wc * 64 + n * 16 + lo;
      for (int r = 0; r < 4; ++r)
        C[(row0 + r) * (long)N + col] = acc[m][n][r];
    }
  }
}

// ---------------- flash attention: 8-wave blocks, EQUAL 512-key chunks, permuted-K, no P-LDS ----------------
// Round-16 mapping (1728 blocks, lengths 2-8 iters, 24 units x 72 blocks, 3 units/XCD).
// NEW: softmax pack via v_cvt_pk_bf16_f32 (1 inst / 2 values) -- __float2bfloat16 is a
// ~4-inst software RNE, and the pack step was ~70 of ~150 VALU inst/iter (VALUBusy ~50%).
// K rows staged PERMUTED (pi) so each lane's softmax outputs ARE its PV A-fragment.
// Causal key: k0 + (kt>>1)*32 + (kt&1)*4 + hi*8 + r.
__global__ __launch_bounds__(512, 4) void flash_attn(const ushort* __restrict__ Q,
                                                     const ushort* __restrict__ Kb,
                                                     const ushort* __restrict__ Vt,
                                                     char* __restrict__ part) {
  const int n    = blockIdx.x;
  const int slot = n >> 3;
  const int u    = slot / 72;                       // unit slot within XCD (0..2)
  int b          = slot - u * 72;                   // block index within unit
  const int unit = (n & 7) * 3 + u;                 // 0..23
  const int h    = unit >> 1;
  const int par  = unit & 1;
  const int top  = par ? 31 : 30;
  int qb = 0, cc = 0;
#pragma unroll 1
  for (int j = 0; j < 16; ++j) {                    // decode b -> (qb, cc), longest-qb first
    int q = top - 2 * j;
    int nc = (q >> 2) + 1;
    if (b < nc) { qb = q; cc = b; break; }
    b -= nc;
  }
  const int kstart  = cc << 9;
  const int blk_lim = qb * 128 + 128;
  const int kend = (kstart + 512 < blk_lim) ? kstart + 512 : blk_lim;

  __shared__ ushort Ks[2][4096];   // [64 rows][64 bf16], rows key-permuted, chunks XOR-swizzled
  __shared__ ushort Vs[2][4096];

  const int t = threadIdx.x;
  const int w = t >> 6, l = t & 63;
  const int lo = l & 15, hi = l >> 4, lo7 = l & 7;
  const int qrow0 = qb * 128 + w * 16;
  const int qlim  = qrow0 + 16;
  const int qabs  = qrow0 + lo;
  const long hT   = (long)h * T_SEQ;
  const long hT64 = (long)h * 64;

  const int srow8 = l >> 3;               // 0..7: row within this wave's 8-row group
  const int row_w = w * 8 + srow8;        // 0..63: LDS tile row this lane stages
  const int prow  = ((row_w >> 5) & 1) * 32 + ((row_w >> 2) & 3) * 8 +
                    ((row_w >> 4) & 1) * 4 + (row_w & 3);   // pi(row_w): source K key
  const int schk  = (l & 7) ^ srow8;      // inverse-swizzled source 16B-chunk

  bf16x8 qf0, qf1;
  {
    const ushort* qp = Q + (hT + qrow0 + lo) * 64 + hi * 8;
    qf0 = *(const bf16x8*)qp;
    qf1 = *(const bf16x8*)(qp + 32);
  }
  f32x4 o[4] = {};
  float m = -1e30f, lsum = 0.0f;

#define STAGE(buf, k0s)                                                         \
  {                                                                             \
    gload_lds16(Kb + (hT + (k0s) + prow) * 64 + schk * 8,                       \
                (char*)&Ks[buf][0] + w * 1024);                                 \
    gload_lds16(Vt + (hT64 + row_w) * T_SEQ + (k0s) + schk * 8,                 \
                (char*)&Vs[buf][0] + w * 1024);                                 \
  }

  STAGE(0, kstart);
  __syncthreads();
  int buf = 0;

  for (int k0 = kstart; k0 < kend; k0 += 64) {
    if (k0 + 64 < kend) STAGE(buf ^ 1, k0 + 64);
    if (k0 < qlim) {
      const ushort* kt_ = &Ks[buf][0];
      const ushort* vt_ = &Vs[buf][0];
      // --- S^T = K . Q^T from swizzled LDS (rows key-permuted) ---
      f32x4 s[4];
      __builtin_amdgcn_s_setprio(1);
#pragma unroll
      for (int kt = 0; kt < 4; ++kt) {
        int rr = kt * 16 + lo;
        bf16x8 ka = *(const bf16x8*)(kt_ + rr * 64 + ((hi ^ lo7) * 8));
        bf16x8 kc = *(const bf16x8*)(kt_ + rr * 64 + (((4 + hi) ^ lo7) * 8));
        f32x4 a = {};
        a = __builtin_amdgcn_mfma_f32_16x16x32_bf16(ka, qf0, a, 0, 0, 0);
        a = __builtin_amdgcn_mfma_f32_16x16x32_bf16(kc, qf1, a, 0, 0, 0);
        s[kt] = a;
      }
      __builtin_amdgcn_s_setprio(0);
      // --- V fragments early (latency overlaps softmax) ---
      bf16x8 vf[8];
#pragma unroll
      for (int dt = 0; dt < 4; ++dt)
#pragma unroll
        for (int cv = 0; cv < 2; ++cv) {
          int rr = dt * 16 + lo;
          vf[dt * 2 + cv] = *(const bf16x8*)(vt_ + rr * 64 + (((cv * 4 + hi) ^ lo7) * 8));
        }
      // --- causal mask (diagonal tiles only); key honors the row permutation ---
      if (k0 + 64 > qrow0) {
#pragma unroll
        for (int kt = 0; kt < 4; ++kt) {
          const int bkt = (kt >> 1) * 32 + (kt & 1) * 4;
#pragma unroll
          for (int r = 0; r < 4; ++r) {
            int key = k0 + bkt + hi * 8 + r;
            if (key > qabs) s[kt][r] = -1e30f;
          }
        }
      }
      // --- row max: 15 in-lane fmax + 2 shfl ---
      float mt = s[0][0];
#pragma unroll
      for (int kt = 0; kt < 4; ++kt)
#pragma unroll
        for (int r = 0; r < 4; ++r) mt = fmaxf(mt, s[kt][r]);
      mt = fmaxf(mt, __shfl_xor(mt, 16));
      mt = fmaxf(mt, __shfl_xor(mt, 32));
      // --- defer-max rescale (THR=8 in log2 domain) ---
      if (!__all(mt - m <= 8.0f)) {
        float mn = fmaxf(m, mt);
        float alpha = EXP2F(m - mn);
        m = mn;
        lsum *= alpha;
#pragma unroll
        for (int r = 0; r < 4; ++r) {
          float ar = __shfl(alpha, hi * 4 + r);
#pragma unroll
          for (int dt = 0; dt < 4; ++dt) o[dt][r] *= ar;
        }
      }
      // --- exp2 + per-lane sum + pack P via v_cvt_pk_bf16_f32 ---
      uint us[8];
#pragma unroll
      for (int kt = 0; kt < 4; ++kt) {
        float p0 = EXP2F(s[kt][0] - m);
        float p1 = EXP2F(s[kt][1] - m);
        float p2 = EXP2F(s[kt][2] - m);
        float p3 = EXP2F(s[kt][3] - m);
        lsum += (p0 + p1) + (p2 + p3);
        us[kt * 2]     = cvt_pk_bf16(p0, p1);
        us[kt * 2 + 1] = cvt_pk_bf16(p2, p3);
      }
      // --- PV: A-fragment is a pure register reassembly ---
      __builtin_amdgcn_s_setprio(1);
#pragma unroll
      for (int cv = 0; cv < 2; ++cv) {
        union { uint4 q; bf16x8 v; } pc;
        pc.q.x = us[cv * 4 + 0];
        pc.q.y = us[cv * 4 + 1];
        pc.q.z = us[cv * 4 + 2];
        pc.q.w = us[cv * 4 + 3];
#pragma unroll
        for (int dt = 0; dt < 4; ++dt)
          o[dt] = __builtin_amdgcn_mfma_f32_16x16x32_bf16(pc.v, vf[dt * 2 + cv], o[dt], 0, 0, 0);
      }
      __builtin_amdgcn_s_setprio(0);
    }
    __syncthreads();
    buf ^= 1;
  }
#undef STAGE

  // --- write partial (unnormalized); compact prefix-indexed slot ---
  if (kstart < qlim) {
    lsum += __shfl_xor(lsum, 16);
    lsum += __shfl_xor(lsum, 32);
    const int g  = qb >> 2;
    const int rr = 8 * (qb & 3) + w;
    const long slotp = (long)h * 1152 + 16 * g * (g + 1) + rr * (g + 1) + cc;
    char* pb = part + slotp * 2176;
    ushort* po = (ushort*)pb;
#pragma unroll
    for (int dt = 0; dt < 4; ++dt)
#pragma unroll
      for (int r = 0; r < 4; ++r)
        po[(hi * 4 + r) * 64 + dt * 16 + lo] = f2b(o[dt][r]);
    if (hi == 0) {
      ((float*)(pb + 2048))[lo] = m;
      ((float*)(pb + 2112))[lo] = lsum;
    }
  }
}

// ---------------- split-K combine (vectorized: 4 rows x 4 cols per thread, ushort4 loads) ----------------
__global__ __launch_bounds__(64) void flash_combine(const char* __restrict__ part,
                                                    ushort* __restrict__ Y) {
  const int qg = blockIdx.x, h = blockIdx.y;
  const int dg = threadIdx.x & 15;       // 4-col group: cols dg*4 .. dg*4+3
  const int rg = threadIdx.x >> 4;       // 4-row group: rows rg*4 .. rg*4+3
  const int qrow0 = qg * 16;
  const int g = qg >> 5, rr = qg & 31;
  const int nch = g + 1;
  const char* ub = part + ((long)h * 1152 + 16 * g * (g + 1) + (long)rr * (g + 1)) * 2176;
  float Mg[4];
#pragma unroll
  for (int r = 0; r < 4; ++r) Mg[r] = -1e30f;
  for (int cc = 0; cc < nch; ++cc) {
    const float* mp = (const float*)(ub + cc * 2176 + 2048);
#pragma unroll
    for (int r = 0; r < 4; ++r) Mg[r] = fmaxf(Mg[r], mp[rg * 4 + r]);
  }
  float acc[4][4] = {};
  float lg[4] = {};
  for (int cc = 0; cc < nch; ++cc) {
    const ushort* op = (const ushort*)(ub + cc * 2176);
    const float* mp = (const float*)(ub + cc * 2176 + 2048);
    const float* lp = (const float*)(ub + cc * 2176 + 2112);
#pragma unroll
    for (int r = 0; r < 4; ++r) {
      const int ra = rg * 4 + r;
      float wgt = EXP2F(mp[ra] - Mg[r]);
      ushort4 v = *(const ushort4*)(op + ra * 64 + dg * 4);
      acc[r][0] += wgt * b2f(v.x);
      acc[r][1] += wgt * b2f(v.y);
      acc[r][2] += wgt * b2f(v.z);
      acc[r][3] += wgt * b2f(v.w);
      lg[r] += wgt * lp[ra];
    }
  }
#pragma unroll
  for (int r = 0; r < 4; ++r) {
    const float inv = 1.0f / lg[r];
    uint2 wv;
    wv.x = cvt_pk_bf16(acc[r][0] * inv, acc[r][1] * inv);
    wv.y = cvt_pk_bf16(acc[r][2] * inv, acc[r][3] * inv);
    *(uint2*)(Y + (long)(qrow0 + rg * 4 + r) * 768 + h * 64 + dg * 4) = wv;
  }
}

extern "C" void kernel_launch(void* const* d_in, const int* in_sizes, int n_in,
                              void* d_out, int out_size, void* d_ws, size_t ws_size,
                              hipStream_t stream) {
  const float* x      = (const float*)d_in[0];
  const float* w_attn = (const float*)d_in[1];
  const float* w_proj = (const float*)d_in[2];
  float* out = (float*)d_out;
  char* ws = (char*)d_ws;

  ushort* xb   = (ushort*)(ws);                 // 4096*768
  ushort* wAb  = (ushort*)(ws + 6291456);       // 2304*768
  ushort* wPb  = (ushort*)(ws + 9830400);       // 768*768
  float*  cosT = (float*)(ws + 11010048);       // 4096*32
  float*  sinT = (float*)(ws + 11534336);
  char*   partR = (ws + 12058624);              // flash split-K partials (compact, 30.1MB)
  ushort* Qb   = (ushort*)(ws + 49807360);      // [12][4096][64]
  ushort* Kbb  = (ushort*)(ws + 56098816);
  ushort* Vt   = (ushort*)(ws + 62390272);      // [12][64][4096]
  ushort* Yb   = (ushort*)(ws + 68681728);      // [4096][768]

  prep_all<<<2752, 256, 0, stream>>>(x, w_attn, w_proj, xb, wAb, wPb, cosT, sinT);
  gemm_qkv<<<576, 256, 0, stream>>>(xb, wAb, cosT, sinT, Qb, Kbb, Vt);
  flash_attn<<<1728, 512, 0, stream>>>(Qb, Kbb, Vt, partR);
  flash_combine<<<dim3(256, NH), 64, 0, stream>>>(partR, Yb);
  gemm_bt<<<192, 256, 0, stream>>>(Yb, wPb, out, 4096, 768, 768);
}

// Round 19
// 123.036 us; speedup vs baseline: 1.0992x; 1.0240x over previous
//
#include <hip/hip_runtime.h>
#include <hip/hip_bf16.h>
#include <stdint.h>

#define T_SEQ 4096
#define NH 12

#if __has_builtin(__builtin_amdgcn_exp2f)
#define EXP2F __builtin_amdgcn_exp2f
#else
#define EXP2F exp2f
#endif

typedef __attribute__((ext_vector_type(4))) float f32x4;
typedef __attribute__((ext_vector_type(8))) __bf16 bf16x8;

__device__ inline ushort f2b(float f) {
  __hip_bfloat16 h = __float2bfloat16(f);
  return *reinterpret_cast<ushort*>(&h);
}
__device__ inline float b2f(ushort u) {
  union { uint i; float f; } v; v.i = (uint)u << 16; return v.f;
}
// one-instruction packed f32x2 -> bf16x2 (operand order proven by r17)
__device__ inline uint cvt_pk_bf16(float a, float b) {
  uint r;
  asm("v_cvt_pk_bf16_f32 %0, %1, %2" : "=v"(r) : "v"(a), "v"(b));
  return r;
}
__device__ inline float max3f(float a, float b, float c) {
  return fmaxf(fmaxf(a, b), c);   // clang fuses to v_max3_f32
}

__device__ inline void gload_lds16(const void* g, void* lds) {
  auto g1 = (const __attribute__((address_space(1))) uint32_t*)(uintptr_t)g;
  auto l3 = (__attribute__((address_space(3))) uint32_t*)(uintptr_t)lds;
  __builtin_amdgcn_global_load_lds(g1, l3, 16, 0, 0);
}

// ---------------- fused prep: 3x fp32->bf16 convert + RoPE tables, one launch ----------------
__global__ __launch_bounds__(256) void prep_all(const float* __restrict__ x,
                                                const float* __restrict__ wA,
                                                const float* __restrict__ wP,
                                                ushort* __restrict__ xb,
                                                ushort* __restrict__ wAb,
                                                ushort* __restrict__ wPb,
                                                float* __restrict__ cosT,
                                                float* __restrict__ sinT) {
  const int u = blockIdx.x * blockDim.x + threadIdx.x;
  if (u < 688128) {
    const float* src;
    ushort* dst;
    long i;
    if (u < 393216)      { src = x;  dst = xb;  i = u; }
    else if (u < 614400) { src = wA; dst = wAb; i = u - 393216; }
    else                 { src = wP; dst = wPb; i = u - 614400; }
    const float4* s4 = (const float4*)src;
    float4 a = s4[i * 2], b = s4[i * 2 + 1];
    uint4 o;
    o.x = (uint)f2b(a.x) | ((uint)f2b(a.y) << 16);
    o.y = (uint)f2b(a.z) | ((uint)f2b(a.w) << 16);
    o.z = (uint)f2b(b.x) | ((uint)f2b(b.y) << 16);
    o.w = (uint)f2b(b.z) | ((uint)f2b(b.w) << 16);
    *(uint4*)(dst + i * 8) = o;
  } else if (u < 704512) {
    const int base = (u - 688128) * 8;   // i = t*32 + d
    const int t = base >> 5;
#pragma unroll
    for (int j = 0; j < 8; ++j) {
      const int d = (base + j) & 31;
      float theta = EXP2F((float)d * (-13.28771238f / 32.0f));  // 10000^(-d/32)
      float a = (float)t * theta;
      cosT[base + j] = cosf(a);
      sinT[base + j] = sinf(a);
    }
  }
}

// ---------------- GEMM1 + fused RoPE/reorder epilogue (1D grid, XCD-swizzled) ----------------
__global__ __launch_bounds__(256) void gemm_qkv(const ushort* __restrict__ A,
                                                const ushort* __restrict__ B,
                                                const float* __restrict__ cosT,
                                                const float* __restrict__ sinT,
                                                ushort* __restrict__ Q,
                                                ushort* __restrict__ Kb,
                                                ushort* __restrict__ Vt) {
  __shared__ ushort As[128 * 64];
  __shared__ ushort Bs[128 * 64];
  const int wg = (blockIdx.x & 7) * 72 + (blockIdx.x >> 3);
  const int bx = wg % 18;
  const int by = wg / 18;
  const int t = threadIdx.x;
  const int w = t >> 6, l = t & 63;
  const int lo = l & 15, hi = l >> 4;
  const int wr = w >> 1, wc = w & 1;
  const long arow = (long)by * 128;
  const long brow = (long)bx * 128;
  const int K = 768;
  f32x4 acc[4][4] = {};
  for (int k0 = 0; k0 < K; k0 += 64) {
    for (int i = 0; i < 4; ++i) {
      int e = i * 2048 + t * 8;
      int r = e >> 6, c = e & 63;
      const ushort* ga = A + (arow + r) * (long)K + k0 + c;
      const ushort* gb = B + (brow + r) * (long)K + k0 + c;
      uint32_t ldsoff = i * 4096 + w * 1024;
      gload_lds16(ga, (char*)As + ldsoff);
      gload_lds16(gb, (char*)Bs + ldsoff);
    }
    __syncthreads();
    for (int kk = 0; kk < 2; ++kk) {
      bf16x8 af[4], bfr[4];
      for (int m = 0; m < 4; ++m)
        af[m] = *(const bf16x8*)&As[(wr * 64 + m * 16 + lo) * 64 + kk * 32 + hi * 8];
      for (int n = 0; n < 4; ++n)
        bfr[n] = *(const bf16x8*)&Bs[(wc * 64 + n * 16 + lo) * 64 + kk * 32 + hi * 8];
      for (int m = 0; m < 4; ++m)
        for (int n = 0; n < 4; ++n)
          acc[m][n] = __builtin_amdgcn_mfma_f32_16x16x32_bf16(af[m], bfr[n], acc[m][n], 0, 0, 0);
    }
    __syncthreads();
  }
  // ---- fused epilogue ----
  const int rq = bx / 6;                 // 0=Q, 1=K, 2=V
  const int h  = (bx % 6) * 2 + wc;      // head for this thread's cols
  const long hT = (long)h * T_SEQ;
  if (rq < 2) {
    ushort* dst = (rq == 0) ? Q : Kb;
    const float qsc = (rq == 0) ? 0.125f * 1.44269504f : 1.0f;
#pragma unroll
    for (int m = 0; m < 4; ++m)
#pragma unroll
      for (int r = 0; r < 4; ++r) {
        const long trow = arow + wr * 64 + m * 16 + hi * 4 + r;
        ushort* rowp = dst + (hT + trow) * 64;
        const float* cp = cosT + trow * 32;
        const float* sp = sinT + trow * 32;
#pragma unroll
        for (int n = 0; n < 2; ++n) {
          const int dd = n * 16 + lo;
          const float cs = cp[dd], sn = sp[dd];
          const float a = acc[m][n][r], b = acc[m][n + 2][r];
          rowp[dd]      = f2b((a * cs - b * sn) * qsc);
          rowp[dd + 32] = f2b((a * sn + b * cs) * qsc);
        }
      }
  } else {
#pragma unroll
    for (int m = 0; m < 4; ++m) {
      const long trow0 = arow + wr * 64 + m * 16 + hi * 4;
#pragma unroll
      for (int n = 0; n < 4; ++n) {
        const int d = n * 16 + lo;
        uint2 pk;
        pk.x = (uint)f2b(acc[m][n][0]) | ((uint)f2b(acc[m][n][1]) << 16);
        pk.y = (uint)f2b(acc[m][n][2]) | ((uint)f2b(acc[m][n][3]) << 16);
        *(uint2*)(Vt + ((long)h * 64 + d) * T_SEQ + trow0) = pk;
      }
    }
  }
}

// ---------------- bf16 GEMM, C = A * B^T (fp32 out; out-proj; 1D grid, XCD-swizzled) ----------------
__global__ __launch_bounds__(256) void gemm_bt(const ushort* __restrict__ A,
                                               const ushort* __restrict__ B,
                                               float* __restrict__ C,
                                               int M, int N, int K) {
  __shared__ ushort As[128 * 64];
  __shared__ ushort Bs[128 * 64];
  const int nbx = N >> 7;
  const int nwg = (M >> 7) * nbx;
  const int cpx = nwg >> 3;
  const int wg = (blockIdx.x & 7) * cpx + (blockIdx.x >> 3);
  const int bx = wg % nbx;
  const int by = wg / nbx;
  const int t = threadIdx.x;
  const int w = t >> 6, l = t & 63;
  const int lo = l & 15, hi = l >> 4;
  const int wr = w >> 1, wc = w & 1;
  const long arow = (long)by * 128;
  const long brow = (long)bx * 128;
  f32x4 acc[4][4] = {};
  for (int k0 = 0; k0 < K; k0 += 64) {
    for (int i = 0; i < 4; ++i) {
      int e = i * 2048 + t * 8;
      int r = e >> 6, c = e & 63;
      const ushort* ga = A + (arow + r) * (long)K + k0 + c;
      const ushort* gb = B + (brow + r) * (long)K + k0 + c;
      uint32_t ldsoff = i * 4096 + w * 1024;
      gload_lds16(ga, (char*)As + ldsoff);
      gload_lds16(gb, (char*)Bs + ldsoff);
    }
    __syncthreads();
    for (int kk = 0; kk < 2; ++kk) {
      bf16x8 af[4], bfr[4];
      for (int m = 0; m < 4; ++m)
        af[m] = *(const bf16x8*)&As[(wr * 64 + m * 16 + lo) * 64 + kk * 32 + hi * 8];
      for (int n = 0; n < 4; ++n)
        bfr[n] = *(const bf16x8*)&Bs[(wc * 64 + n * 16 + lo) * 64 + kk * 32 + hi * 8];
      for (int m = 0; m < 4; ++m)
        for (int n = 0; n < 4; ++n)
          acc[m][n] = __builtin_amdgcn_mfma_f32_16x16x32_bf16(af[m], bfr[n], acc[m][n], 0, 0, 0);
    }
    __syncthreads();
  }
  for (int m = 0; m < 4; ++m) {
    long row0 = arow + wr * 64 + m * 16 + hi * 4;
    for (int n = 0; n < 4; ++n) {
      long col = brow + wc * 64 + n * 16 + lo;
      for (int r = 0; r < 4; ++r)
        C[(row0 + r) * (long)N + col] = acc[m][n][r];
    }
  }
}

// ---------------- flash attention: 8-wave blocks, 512-key chunks, permuted-K, no P-LDS ----------------
// r17 structure (known-good) + max3 row-max tree only. NO unroll-2, NO MFMA-lsum (r18's
// combined changes produced a stale-buffer-class failure; one risky change per round).
// K rows staged PERMUTED (pi) so each lane's softmax outputs ARE its PV A-fragment.
// Causal key: k0 + (kt>>1)*32 + (kt&1)*4 + hi*8 + r.
__global__ __launch_bounds__(512, 4) void flash_attn(const ushort* __restrict__ Q,
                                                     const ushort* __restrict__ Kb,
                                                     const ushort* __restrict__ Vt,
                                                     char* __restrict__ part) {
  const int n    = blockIdx.x;
  const int slot = n >> 3;
  const int u    = slot / 72;                       // unit slot within XCD (0..2)
  int b          = slot - u * 72;                   // block index within unit
  const int unit = (n & 7) * 3 + u;                 // 0..23
  const int h    = unit >> 1;
  const int par  = unit & 1;
  const int top  = par ? 31 : 30;
  int qb = 0, cc = 0;
#pragma unroll 1
  for (int j = 0; j < 16; ++j) {                    // decode b -> (qb, cc), longest-qb first
    int q = top - 2 * j;
    int nc = (q >> 2) + 1;
    if (b < nc) { qb = q; cc = b; break; }
    b -= nc;
  }
  const int kstart  = cc << 9;
  const int blk_lim = qb * 128 + 128;
  const int kend = (kstart + 512 < blk_lim) ? kstart + 512 : blk_lim;

  __shared__ ushort Ks[2][4096];   // [64 rows][64 bf16], rows key-permuted, chunks XOR-swizzled
  __shared__ ushort Vs[2][4096];

  const int t = threadIdx.x;
  const int w = t >> 6, l = t & 63;
  const int lo = l & 15, hi = l >> 4, lo7 = l & 7;
  const int qrow0 = qb * 128 + w * 16;
  const int qlim  = qrow0 + 16;
  const int qabs  = qrow0 + lo;
  const long hT   = (long)h * T_SEQ;
  const long hT64 = (long)h * 64;

  const int srow8 = l >> 3;               // 0..7: row within this wave's 8-row group
  const int row_w = w * 8 + srow8;        // 0..63: LDS tile row this lane stages
  const int prow  = ((row_w >> 5) & 1) * 32 + ((row_w >> 2) & 3) * 8 +
                    ((row_w >> 4) & 1) * 4 + (row_w & 3);   // pi(row_w): source K key
  const int schk  = (l & 7) ^ srow8;      // inverse-swizzled source 16B-chunk

  bf16x8 qf0, qf1;
  {
    const ushort* qp = Q + (hT + qrow0 + lo) * 64 + hi * 8;
    qf0 = *(const bf16x8*)qp;
    qf1 = *(const bf16x8*)(qp + 32);
  }
  f32x4 o[4] = {};
  float m = -1e30f, lsum = 0.0f;

#define STAGE(buf, k0s)                                                         \
  {                                                                             \
    gload_lds16(Kb + (hT + (k0s) + prow) * 64 + schk * 8,                       \
                (char*)&Ks[buf][0] + w * 1024);                                 \
    gload_lds16(Vt + (hT64 + row_w) * T_SEQ + (k0s) + schk * 8,                 \
                (char*)&Vs[buf][0] + w * 1024);                                 \
  }

  STAGE(0, kstart);
  __syncthreads();
  int buf = 0;

  for (int k0 = kstart; k0 < kend; k0 += 64) {
    if (k0 + 64 < kend) STAGE(buf ^ 1, k0 + 64);
    if (k0 < qlim) {
      const ushort* kt_ = &Ks[buf][0];
      const ushort* vt_ = &Vs[buf][0];
      // --- S^T = K . Q^T from swizzled LDS (rows key-permuted) ---
      f32x4 s[4];
      __builtin_amdgcn_s_setprio(1);
#pragma unroll
      for (int kt = 0; kt < 4; ++kt) {
        int rr = kt * 16 + lo;
        bf16x8 ka = *(const bf16x8*)(kt_ + rr * 64 + ((hi ^ lo7) * 8));
        bf16x8 kc = *(const bf16x8*)(kt_ + rr * 64 + (((4 + hi) ^ lo7) * 8));
        f32x4 a = {};
        a = __builtin_amdgcn_mfma_f32_16x16x32_bf16(ka, qf0, a, 0, 0, 0);
        a = __builtin_amdgcn_mfma_f32_16x16x32_bf16(kc, qf1, a, 0, 0, 0);
        s[kt] = a;
      }
      __builtin_amdgcn_s_setprio(0);
      // --- V fragments early (latency overlaps softmax) ---
      bf16x8 vf[8];
#pragma unroll
      for (int dt = 0; dt < 4; ++dt)
#pragma unroll
        for (int cv = 0; cv < 2; ++cv) {
          int rr = dt * 16 + lo;
          vf[dt * 2 + cv] = *(const bf16x8*)(vt_ + rr * 64 + (((cv * 4 + hi) ^ lo7) * 8));
        }
      // --- causal mask (diagonal tiles only); key honors the row permutation ---
      if (k0 + 64 > qrow0) {
#pragma unroll
        for (int kt = 0; kt < 4; ++kt) {
          const int bkt = (kt >> 1) * 32 + (kt & 1) * 4;
#pragma unroll
          for (int r = 0; r < 4; ++r) {
            int key = k0 + bkt + hi * 8 + r;
            if (key > qabs) s[kt][r] = -1e30f;
          }
        }
      }
      // --- row max: max3 tree + 2 shfl ---
      float m1 = max3f(s[0][0], s[0][1], s[0][2]);
      float m2 = max3f(s[0][3], s[1][0], s[1][1]);
      float m3 = max3f(s[1][2], s[1][3], s[2][0]);
      float m4 = max3f(s[2][1], s[2][2], s[2][3]);
      float m5 = max3f(s[3][0], s[3][1], s[3][2]);
      float mt = max3f(max3f(m1, m2, m3), max3f(m4, m5, s[3][3]), -1e30f);
      mt = fmaxf(mt, __shfl_xor(mt, 16));
      mt = fmaxf(mt, __shfl_xor(mt, 32));
      // --- defer-max rescale (THR=8 in log2 domain) ---
      if (!__all(mt - m <= 8.0f)) {
        float mn = fmaxf(m, mt);
        float alpha = EXP2F(m - mn);
        m = mn;
        lsum *= alpha;
#pragma unroll
        for (int r = 0; r < 4; ++r) {
          float ar = __shfl(alpha, hi * 4 + r);
#pragma unroll
          for (int dt = 0; dt < 4; ++dt) o[dt][r] *= ar;
        }
      }
      // --- exp2 + per-lane sum + pack P via v_cvt_pk_bf16_f32 ---
      uint us[8];
#pragma unroll
      for (int kt = 0; kt < 4; ++kt) {
        float p0 = EXP2F(s[kt][0] - m);
        float p1 = EXP2F(s[kt][1] - m);
        float p2 = EXP2F(s[kt][2] - m);
        float p3 = EXP2F(s[kt][3] - m);
        lsum += (p0 + p1) + (p2 + p3);
        us[kt * 2]     = cvt_pk_bf16(p0, p1);
        us[kt * 2 + 1] = cvt_pk_bf16(p2, p3);
      }
      // --- PV: A-fragment is a pure register reassembly ---
      __builtin_amdgcn_s_setprio(1);
#pragma unroll
      for (int cv = 0; cv < 2; ++cv) {
        union { uint4 q; bf16x8 v; } pc;
        pc.q.x = us[cv * 4 + 0];
        pc.q.y = us[cv * 4 + 1];
        pc.q.z = us[cv * 4 + 2];
        pc.q.w = us[cv * 4 + 3];
#pragma unroll
        for (int dt = 0; dt < 4; ++dt)
          o[dt] = __builtin_amdgcn_mfma_f32_16x16x32_bf16(pc.v, vf[dt * 2 + cv], o[dt], 0, 0, 0);
      }
      __builtin_amdgcn_s_setprio(0);
    }
    __syncthreads();
    buf ^= 1;
  }
#undef STAGE

  // --- write partial (unnormalized); compact prefix-indexed slot ---
  if (kstart < qlim) {
    lsum += __shfl_xor(lsum, 16);
    lsum += __shfl_xor(lsum, 32);
    const int g  = qb >> 2;
    const int rr = 8 * (qb & 3) + w;
    const long slotp = (long)h * 1152 + 16 * g * (g + 1) + rr * (g + 1) + cc;
    char* pb = part + slotp * 2176;
    ushort* po = (ushort*)pb;
#pragma unroll
    for (int dt = 0; dt < 4; ++dt)
#pragma unroll
      for (int r = 0; r < 4; ++r)
        po[(hi * 4 + r) * 64 + dt * 16 + lo] = f2b(o[dt][r]);
    if (hi == 0) {
      ((float*)(pb + 2048))[lo] = m;
      ((float*)(pb + 2112))[lo] = lsum;
    }
  }
}

// ---------------- split-K combine (vectorized: 4 rows x 4 cols per thread, ushort4 loads) ----------------
__global__ __launch_bounds__(64) void flash_combine(const char* __restrict__ part,
                                                    ushort* __restrict__ Y) {
  const int qg = blockIdx.x, h = blockIdx.y;
  const int dg = threadIdx.x & 15;       // 4-col group: cols dg*4 .. dg*4+3
  const int rg = threadIdx.x >> 4;       // 4-row group: rows rg*4 .. rg*4+3
  const int qrow0 = qg * 16;
  const int g = qg >> 5, rr = qg & 31;
  const int nch = g + 1;
  const char* ub = part + ((long)h * 1152 + 16 * g * (g + 1) + (long)rr * (g + 1)) * 2176;
  float Mg[4];
#pragma unroll
  for (int r = 0; r < 4; ++r) Mg[r] = -1e30f;
  for (int cc = 0; cc < nch; ++cc) {
    const float* mp = (const float*)(ub + cc * 2176 + 2048);
#pragma unroll
    for (int r = 0; r < 4; ++r) Mg[r] = fmaxf(Mg[r], mp[rg * 4 + r]);
  }
  float acc[4][4] = {};
  float lg[4] = {};
  for (int cc = 0; cc < nch; ++cc) {
    const ushort* op = (const ushort*)(ub + cc * 2176);
    const float* mp = (const float*)(ub + cc * 2176 + 2048);
    const float* lp = (const float*)(ub + cc * 2176 + 2112);
#pragma unroll
    for (int r = 0; r < 4; ++r) {
      const int ra = rg * 4 + r;
      float wgt = EXP2F(mp[ra] - Mg[r]);
      ushort4 v = *(const ushort4*)(op + ra * 64 + dg * 4);
      acc[r][0] += wgt * b2f(v.x);
      acc[r][1] += wgt * b2f(v.y);
      acc[r][2] += wgt * b2f(v.z);
      acc[r][3] += wgt * b2f(v.w);
      lg[r] += wgt * lp[ra];
    }
  }
#pragma unroll
  for (int r = 0; r < 4; ++r) {
    const float inv = 1.0f / lg[r];
    uint2 wv;
    wv.x = cvt_pk_bf16(acc[r][0] * inv, acc[r][1] * inv);
    wv.y = cvt_pk_bf16(acc[r][2] * inv, acc[r][3] * inv);
    *(uint2*)(Y + (long)(qrow0 + rg * 4 + r) * 768 + h * 64 + dg * 4) = wv;
  }
}

extern "C" void kernel_launch(void* const* d_in, const int* in_sizes, int n_in,
                              void* d_out, int out_size, void* d_ws, size_t ws_size,
                              hipStream_t stream) {
  const float* x      = (const float*)d_in[0];
  const float* w_attn = (const float*)d_in[1];
  const float* w_proj = (const float*)d_in[2];
  float* out = (float*)d_out;
  char* ws = (char*)d_ws;

  ushort* xb   = (ushort*)(ws);                 // 4096*768
  ushort* wAb  = (ushort*)(ws + 6291456);       // 2304*768
  ushort* wPb  = (ushort*)(ws + 9830400);       // 768*768
  float*  cosT = (float*)(ws + 11010048);       // 4096*32
  float*  sinT = (float*)(ws + 11534336);
  char*   partR = (ws + 12058624);              // flash split-K partials (compact, 30.1MB)
  ushort* Qb   = (ushort*)(ws + 49807360);      // [12][4096][64]
  ushort* Kbb  = (ushort*)(ws + 56098816);
  ushort* Vt   = (ushort*)(ws + 62390272);      // [12][64][4096]
  ushort* Yb   = (ushort*)(ws + 68681728);      // [4096][768]

  prep_all<<<2752, 256, 0, stream>>>(x, w_attn, w_proj, xb, wAb, wPb, cosT, sinT);
  gemm_qkv<<<576, 256, 0, stream>>>(xb, wAb, cosT, sinT, Qb, Kbb, Vt);
  flash_attn<<<1728, 512, 0, stream>>>(Qb, Kbb, Vt, partR);
  flash_combine<<<dim3(256, NH), 64, 0, stream>>>(partR, Yb);
  gemm_bt<<<192, 256, 0, stream>>>(Yb, wPb, out, 4096, 768, 768);
}

// Round 20
// 107.351 us; speedup vs baseline: 1.2598x; 1.1461x over previous
//
#include <hip/hip_runtime.h>
#include <hip/hip_bf16.h>
#include <stdint.h>

#define T_SEQ 4096
#define NH 12

#if __has_builtin(__builtin_amdgcn_exp2f)
#define EXP2F __builtin_amdgcn_exp2f
#else
#define EXP2F exp2f
#endif

typedef __attribute__((ext_vector_type(4))) float f32x4;
typedef __attribute__((ext_vector_type(8))) __bf16 bf16x8;

__device__ inline ushort f2b(float f) {
  __hip_bfloat16 h = __float2bfloat16(f);
  return *reinterpret_cast<ushort*>(&h);
}
__device__ inline float b2f(ushort u) {
  union { uint i; float f; } v; v.i = (uint)u << 16; return v.f;
}
// one-instruction packed f32x2 -> bf16x2 (operand order proven by r17)
__device__ inline uint cvt_pk_bf16(float a, float b) {
  uint r;
  asm("v_cvt_pk_bf16_f32 %0, %1, %2" : "=v"(r) : "v"(a), "v"(b));
  return r;
}
__device__ inline float max3f(float a, float b, float c) {
  return fmaxf(fmaxf(a, b), c);   // clang fuses to v_max3_f32
}

__device__ inline void gload_lds16(const void* g, void* lds) {
  auto g1 = (const __attribute__((address_space(1))) uint32_t*)(uintptr_t)g;
  auto l3 = (__attribute__((address_space(3))) uint32_t*)(uintptr_t)lds;
  __builtin_amdgcn_global_load_lds(g1, l3, 16, 0, 0);
}

// ---------------- fused prep: 3x fp32->bf16 convert + RoPE tables, one launch ----------------
__global__ __launch_bounds__(256) void prep_all(const float* __restrict__ x,
                                                const float* __restrict__ wA,
                                                const float* __restrict__ wP,
                                                ushort* __restrict__ xb,
                                                ushort* __restrict__ wAb,
                                                ushort* __restrict__ wPb,
                                                float* __restrict__ cosT,
                                                float* __restrict__ sinT) {
  const int u = blockIdx.x * blockDim.x + threadIdx.x;
  if (u < 688128) {
    const float* src;
    ushort* dst;
    long i;
    if (u < 393216)      { src = x;  dst = xb;  i = u; }
    else if (u < 614400) { src = wA; dst = wAb; i = u - 393216; }
    else                 { src = wP; dst = wPb; i = u - 614400; }
    const float4* s4 = (const float4*)src;
    float4 a = s4[i * 2], b = s4[i * 2 + 1];
    uint4 o;
    o.x = (uint)f2b(a.x) | ((uint)f2b(a.y) << 16);
    o.y = (uint)f2b(a.z) | ((uint)f2b(a.w) << 16);
    o.z = (uint)f2b(b.x) | ((uint)f2b(b.y) << 16);
    o.w = (uint)f2b(b.z) | ((uint)f2b(b.w) << 16);
    *(uint4*)(dst + i * 8) = o;
  } else if (u < 704512) {
    const int base = (u - 688128) * 8;   // i = t*32 + d
    const int t = base >> 5;
#pragma unroll
    for (int j = 0; j < 8; ++j) {
      const int d = (base + j) & 31;
      float theta = EXP2F((float)d * (-13.28771238f / 32.0f));  // 10000^(-d/32)
      float a = (float)t * theta;
      cosT[base + j] = cosf(a);
      sinT[base + j] = sinf(a);
    }
  }
}

// ---------------- GEMM1 + fused RoPE/reorder epilogue (dbuf K-loop, 1 barrier/iter) ----------------
__global__ __launch_bounds__(256) void gemm_qkv(const ushort* __restrict__ A,
                                                const ushort* __restrict__ B,
                                                const float* __restrict__ cosT,
                                                const float* __restrict__ sinT,
                                                ushort* __restrict__ Q,
                                                ushort* __restrict__ Kb,
                                                ushort* __restrict__ Vt) {
  __shared__ ushort As[2][8192];
  __shared__ ushort Bs[2][8192];
  const int wg = (blockIdx.x & 7) * 72 + (blockIdx.x >> 3);
  const int bx = wg % 18;
  const int by = wg / 18;
  const int t = threadIdx.x;
  const int w = t >> 6, l = t & 63;
  const int lo = l & 15, hi = l >> 4;
  const int wr = w >> 1, wc = w & 1;
  const long arow = (long)by * 128;
  const long brow = (long)bx * 128;
  const int K = 768;
  f32x4 acc[4][4] = {};

#define GSTAGE(bufg, k0s)                                                       \
  {                                                                             \
    _Pragma("unroll")                                                           \
    for (int i_ = 0; i_ < 4; ++i_) {                                            \
      int e_ = i_ * 2048 + t * 8;                                               \
      int r_ = e_ >> 6, c_ = e_ & 63;                                           \
      gload_lds16(A + (arow + r_) * (long)K + (k0s) + c_,                       \
                  (char*)&As[bufg][0] + i_ * 4096 + w * 1024);                  \
      gload_lds16(B + (brow + r_) * (long)K + (k0s) + c_,                       \
                  (char*)&Bs[bufg][0] + i_ * 4096 + w * 1024);                  \
    }                                                                           \
  }

  GSTAGE(0, 0);
  __syncthreads();
  int bufg = 0;
  for (int k0 = 0; k0 < K; k0 += 64) {
    if (k0 + 64 < K) GSTAGE(bufg ^ 1, k0 + 64);
    for (int kk = 0; kk < 2; ++kk) {
      bf16x8 af[4], bfr[4];
      for (int m = 0; m < 4; ++m)
        af[m] = *(const bf16x8*)&As[bufg][(wr * 64 + m * 16 + lo) * 64 + kk * 32 + hi * 8];
      for (int n = 0; n < 4; ++n)
        bfr[n] = *(const bf16x8*)&Bs[bufg][(wc * 64 + n * 16 + lo) * 64 + kk * 32 + hi * 8];
      for (int m = 0; m < 4; ++m)
        for (int n = 0; n < 4; ++n)
          acc[m][n] = __builtin_amdgcn_mfma_f32_16x16x32_bf16(af[m], bfr[n], acc[m][n], 0, 0, 0);
    }
    __syncthreads();
    bufg ^= 1;
  }
#undef GSTAGE
  // ---- fused epilogue ----
  const int rq = bx / 6;                 // 0=Q, 1=K, 2=V
  const int h  = (bx % 6) * 2 + wc;      // head for this thread's cols
  const long hT = (long)h * T_SEQ;
  if (rq < 2) {
    ushort* dst = (rq == 0) ? Q : Kb;
    const float qsc = (rq == 0) ? 0.125f * 1.44269504f : 1.0f;
#pragma unroll
    for (int m = 0; m < 4; ++m)
#pragma unroll
      for (int r = 0; r < 4; ++r) {
        const long trow = arow + wr * 64 + m * 16 + hi * 4 + r;
        ushort* rowp = dst + (hT + trow) * 64;
        const float* cp = cosT + trow * 32;
        const float* sp = sinT + trow * 32;
#pragma unroll
        for (int n = 0; n < 2; ++n) {
          const int dd = n * 16 + lo;
          const float cs = cp[dd], sn = sp[dd];
          const float a = acc[m][n][r], b = acc[m][n + 2][r];
          rowp[dd]      = f2b((a * cs - b * sn) * qsc);
          rowp[dd + 32] = f2b((a * sn + b * cs) * qsc);
        }
      }
  } else {
#pragma unroll
    for (int m = 0; m < 4; ++m) {
      const long trow0 = arow + wr * 64 + m * 16 + hi * 4;
#pragma unroll
      for (int n = 0; n < 4; ++n) {
        const int d = n * 16 + lo;
        uint2 pk;
        pk.x = (uint)f2b(acc[m][n][0]) | ((uint)f2b(acc[m][n][1]) << 16);
        pk.y = (uint)f2b(acc[m][n][2]) | ((uint)f2b(acc[m][n][3]) << 16);
        *(uint2*)(Vt + ((long)h * 64 + d) * T_SEQ + trow0) = pk;
      }
    }
  }
}

// ---------------- bf16 GEMM, C = A * B^T (fp32 out; out-proj; dbuf K-loop) ----------------
__global__ __launch_bounds__(256) void gemm_bt(const ushort* __restrict__ A,
                                               const ushort* __restrict__ B,
                                               float* __restrict__ C,
                                               int M, int N, int K) {
  __shared__ ushort As[2][8192];
  __shared__ ushort Bs[2][8192];
  const int nbx = N >> 7;
  const int nwg = (M >> 7) * nbx;
  const int cpx = nwg >> 3;
  const int wg = (blockIdx.x & 7) * cpx + (blockIdx.x >> 3);
  const int bx = wg % nbx;
  const int by = wg / nbx;
  const int t = threadIdx.x;
  const int w = t >> 6, l = t & 63;
  const int lo = l & 15, hi = l >> 4;
  const int wr = w >> 1, wc = w & 1;
  const long arow = (long)by * 128;
  const long brow = (long)bx * 128;
  f32x4 acc[4][4] = {};

#define GSTAGE(bufg, k0s)                                                       \
  {                                                                             \
    _Pragma("unroll")                                                           \
    for (int i_ = 0; i_ < 4; ++i_) {                                            \
      int e_ = i_ * 2048 + t * 8;                                               \
      int r_ = e_ >> 6, c_ = e_ & 63;                                           \
      gload_lds16(A + (arow + r_) * (long)K + (k0s) + c_,                       \
                  (char*)&As[bufg][0] + i_ * 4096 + w * 1024);                  \
      gload_lds16(B + (brow + r_) * (long)K + (k0s) + c_,                       \
                  (char*)&Bs[bufg][0] + i_ * 4096 + w * 1024);                  \
    }                                                                           \
  }

  GSTAGE(0, 0);
  __syncthreads();
  int bufg = 0;
  for (int k0 = 0; k0 < K; k0 += 64) {
    if (k0 + 64 < K) GSTAGE(bufg ^ 1, k0 + 64);
    for (int kk = 0; kk < 2; ++kk) {
      bf16x8 af[4], bfr[4];
      for (int m = 0; m < 4; ++m)
        af[m] = *(const bf16x8*)&As[bufg][(wr * 64 + m * 16 + lo) * 64 + kk * 32 + hi * 8];
      for (int n = 0; n < 4; ++n)
        bfr[n] = *(const bf16x8*)&Bs[bufg][(wc * 64 + n * 16 + lo) * 64 + kk * 32 + hi * 8];
      for (int m = 0; m < 4; ++m)
        for (int n = 0; n < 4; ++n)
          acc[m][n] = __builtin_amdgcn_mfma_f32_16x16x32_bf16(af[m], bfr[n], acc[m][n], 0, 0, 0);
    }
    __syncthreads();
    bufg ^= 1;
  }
#undef GSTAGE
  for (int m = 0; m < 4; ++m) {
    long row0 = arow + wr * 64 + m * 16 + hi * 4;
    for (int n = 0; n < 4; ++n) {
      long col = brow + wc * 64 + n * 16 + lo;
      for (int r = 0; r < 4; ++r)
        C[(row0 + r) * (long)N + col] = acc[m][n][r];
    }
  }
}

// ---------------- flash attention: 8-wave blocks, 512-key chunks, permuted-K, no P-LDS ----------------
// r19 state (known-good, 52us): cvt_pk pack, max3 tree, scalar lsum, no unroll pragma.
// K rows staged PERMUTED (pi) so each lane's softmax outputs ARE its PV A-fragment.
// Causal key: k0 + (kt>>1)*32 + (kt&1)*4 + hi*8 + r.
__global__ __launch_bounds__(512, 4) void flash_attn(const ushort* __restrict__ Q,
                                                     const ushort* __restrict__ Kb,
                                                     const ushort* __restrict__ Vt,
                                                     char* __restrict__ part) {
  const int n    = blockIdx.x;
  const int slot = n >> 3;
  const int u    = slot / 72;                       // unit slot within XCD (0..2)
  int b          = slot - u * 72;                   // block index within unit
  const int unit = (n & 7) * 3 + u;                 // 0..23
  const int h    = unit >> 1;
  const int par  = unit & 1;
  const int top  = par ? 31 : 30;
  int qb = 0, cc = 0;
#pragma unroll 1
  for (int j = 0; j < 16; ++j) {                    // decode b -> (qb, cc), longest-qb first
    int q = top - 2 * j;
    int nc = (q >> 2) + 1;
    if (b < nc) { qb = q; cc = b; break; }
    b -= nc;
  }
  const int kstart  = cc << 9;
  const int blk_lim = qb * 128 + 128;
  const int kend = (kstart + 512 < blk_lim) ? kstart + 512 : blk_lim;

  __shared__ ushort Ks[2][4096];   // [64 rows][64 bf16], rows key-permuted, chunks XOR-swizzled
  __shared__ ushort Vs[2][4096];

  const int t = threadIdx.x;
  const int w = t >> 6, l = t & 63;
  const int lo = l & 15, hi = l >> 4, lo7 = l & 7;
  const int qrow0 = qb * 128 + w * 16;
  const int qlim  = qrow0 + 16;
  const int qabs  = qrow0 + lo;
  const long hT   = (long)h * T_SEQ;
  const long hT64 = (long)h * 64;

  const int srow8 = l >> 3;               // 0..7: row within this wave's 8-row group
  const int row_w = w * 8 + srow8;        // 0..63: LDS tile row this lane stages
  const int prow  = ((row_w >> 5) & 1) * 32 + ((row_w >> 2) & 3) * 8 +
                    ((row_w >> 4) & 1) * 4 + (row_w & 3);   // pi(row_w): source K key
  const int schk  = (l & 7) ^ srow8;      // inverse-swizzled source 16B-chunk

  bf16x8 qf0, qf1;
  {
    const ushort* qp = Q + (hT + qrow0 + lo) * 64 + hi * 8;
    qf0 = *(const bf16x8*)qp;
    qf1 = *(const bf16x8*)(qp + 32);
  }
  f32x4 o[4] = {};
  float m = -1e30f, lsum = 0.0f;

#define STAGE(buf, k0s)                                                         \
  {                                                                             \
    gload_lds16(Kb + (hT + (k0s) + prow) * 64 + schk * 8,                       \
                (char*)&Ks[buf][0] + w * 1024);                                 \
    gload_lds16(Vt + (hT64 + row_w) * T_SEQ + (k0s) + schk * 8,                 \
                (char*)&Vs[buf][0] + w * 1024);                                 \
  }

  STAGE(0, kstart);
  __syncthreads();
  int buf = 0;

  for (int k0 = kstart; k0 < kend; k0 += 64) {
    if (k0 + 64 < kend) STAGE(buf ^ 1, k0 + 64);
    if (k0 < qlim) {
      const ushort* kt_ = &Ks[buf][0];
      const ushort* vt_ = &Vs[buf][0];
      // --- S^T = K . Q^T from swizzled LDS (rows key-permuted) ---
      f32x4 s[4];
      __builtin_amdgcn_s_setprio(1);
#pragma unroll
      for (int kt = 0; kt < 4; ++kt) {
        int rr = kt * 16 + lo;
        bf16x8 ka = *(const bf16x8*)(kt_ + rr * 64 + ((hi ^ lo7) * 8));
        bf16x8 kc = *(const bf16x8*)(kt_ + rr * 64 + (((4 + hi) ^ lo7) * 8));
        f32x4 a = {};
        a = __builtin_amdgcn_mfma_f32_16x16x32_bf16(ka, qf0, a, 0, 0, 0);
        a = __builtin_amdgcn_mfma_f32_16x16x32_bf16(kc, qf1, a, 0, 0, 0);
        s[kt] = a;
      }
      __builtin_amdgcn_s_setprio(0);
      // --- V fragments early (latency overlaps softmax) ---
      bf16x8 vf[8];
#pragma unroll
      for (int dt = 0; dt < 4; ++dt)
#pragma unroll
        for (int cv = 0; cv < 2; ++cv) {
          int rr = dt * 16 + lo;
          vf[dt * 2 + cv] = *(const bf16x8*)(vt_ + rr * 64 + (((cv * 4 + hi) ^ lo7) * 8));
        }
      // --- causal mask (diagonal tiles only); key honors the row permutation ---
      if (k0 + 64 > qrow0) {
#pragma unroll
        for (int kt = 0; kt < 4; ++kt) {
          const int bkt = (kt >> 1) * 32 + (kt & 1) * 4;
#pragma unroll
          for (int r = 0; r < 4; ++r) {
            int key = k0 + bkt + hi * 8 + r;
            if (key > qabs) s[kt][r] = -1e30f;
          }
        }
      }
      // --- row max: max3 tree + 2 shfl ---
      float m1 = max3f(s[0][0], s[0][1], s[0][2]);
      float m2 = max3f(s[0][3], s[1][0], s[1][1]);
      float m3 = max3f(s[1][2], s[1][3], s[2][0]);
      float m4 = max3f(s[2][1], s[2][2], s[2][3]);
      float m5 = max3f(s[3][0], s[3][1], s[3][2]);
      float mt = max3f(max3f(m1, m2, m3), max3f(m4, m5, s[3][3]), -1e30f);
      mt = fmaxf(mt, __shfl_xor(mt, 16));
      mt = fmaxf(mt, __shfl_xor(mt, 32));
      // --- defer-max rescale (THR=8 in log2 domain) ---
      if (!__all(mt - m <= 8.0f)) {
        float mn = fmaxf(m, mt);
        float alpha = EXP2F(m - mn);
        m = mn;
        lsum *= alpha;
#pragma unroll
        for (int r = 0; r < 4; ++r) {
          float ar = __shfl(alpha, hi * 4 + r);
#pragma unroll
          for (int dt = 0; dt < 4; ++dt) o[dt][r] *= ar;
        }
      }
      // --- exp2 + per-lane sum + pack P via v_cvt_pk_bf16_f32 ---
      uint us[8];
#pragma unroll
      for (int kt = 0; kt < 4; ++kt) {
        float p0 = EXP2F(s[kt][0] - m);
        float p1 = EXP2F(s[kt][1] - m);
        float p2 = EXP2F(s[kt][2] - m);
        float p3 = EXP2F(s[kt][3] - m);
        lsum += (p0 + p1) + (p2 + p3);
        us[kt * 2]     = cvt_pk_bf16(p0, p1);
        us[kt * 2 + 1] = cvt_pk_bf16(p2, p3);
      }
      // --- PV: A-fragment is a pure register reassembly ---
      __builtin_amdgcn_s_setprio(1);
#pragma unroll
      for (int cv = 0; cv < 2; ++cv) {
        union { uint4 q; bf16x8 v; } pc;
        pc.q.x = us[cv * 4 + 0];
        pc.q.y = us[cv * 4 + 1];
        pc.q.z = us[cv * 4 + 2];
        pc.q.w = us[cv * 4 + 3];
#pragma unroll
        for (int dt = 0; dt < 4; ++dt)
          o[dt] = __builtin_amdgcn_mfma_f32_16x16x32_bf16(pc.v, vf[dt * 2 + cv], o[dt], 0, 0, 0);
      }
      __builtin_amdgcn_s_setprio(0);
    }
    __syncthreads();
    buf ^= 1;
  }
#undef STAGE

  // --- write partial (unnormalized); compact prefix-indexed slot ---
  if (kstart < qlim) {
    lsum += __shfl_xor(lsum, 16);
    lsum += __shfl_xor(lsum, 32);
    const int g  = qb >> 2;
    const int rr = 8 * (qb & 3) + w;
    const long slotp = (long)h * 1152 + 16 * g * (g + 1) + rr * (g + 1) + cc;
    char* pb = part + slotp * 2176;
    ushort* po = (ushort*)pb;
#pragma unroll
    for (int dt = 0; dt < 4; ++dt)
#pragma unroll
      for (int r = 0; r < 4; ++r)
        po[(hi * 4 + r) * 64 + dt * 16 + lo] = f2b(o[dt][r]);
    if (hi == 0) {
      ((float*)(pb + 2048))[lo] = m;
      ((float*)(pb + 2112))[lo] = lsum;
    }
  }
}

// ---------------- split-K combine (vectorized: 4 rows x 4 cols per thread, ushort4 loads) ----------------
__global__ __launch_bounds__(64) void flash_combine(const char* __restrict__ part,
                                                    ushort* __restrict__ Y) {
  const int qg = blockIdx.x, h = blockIdx.y;
  const int dg = threadIdx.x & 15;       // 4-col group: cols dg*4 .. dg*4+3
  const int rg = threadIdx.x >> 4;       // 4-row group: rows rg*4 .. rg*4+3
  const int qrow0 = qg * 16;
  const int g = qg >> 5, rr = qg & 31;
  const int nch = g + 1;
  const char* ub = part + ((long)h * 1152 + 16 * g * (g + 1) + (long)rr * (g + 1)) * 2176;
  float Mg[4];
#pragma unroll
  for (int r = 0; r < 4; ++r) Mg[r] = -1e30f;
  for (int cc = 0; cc < nch; ++cc) {
    const float* mp = (const float*)(ub + cc * 2176 + 2048);
#pragma unroll
    for (int r = 0; r < 4; ++r) Mg[r] = fmaxf(Mg[r], mp[rg * 4 + r]);
  }
  float acc[4][4] = {};
  float lg[4] = {};
  for (int cc = 0; cc < nch; ++cc) {
    const ushort* op = (const ushort*)(ub + cc * 2176);
    const float* mp = (const float*)(ub + cc * 2176 + 2048);
    const float* lp = (const float*)(ub + cc * 2176 + 2112);
#pragma unroll
    for (int r = 0; r < 4; ++r) {
      const int ra = rg * 4 + r;
      float wgt = EXP2F(mp[ra] - Mg[r]);
      ushort4 v = *(const ushort4*)(op + ra * 64 + dg * 4);
      acc[r][0] += wgt * b2f(v.x);
      acc[r][1] += wgt * b2f(v.y);
      acc[r][2] += wgt * b2f(v.z);
      acc[r][3] += wgt * b2f(v.w);
      lg[r] += wgt * lp[ra];
    }
  }
#pragma unroll
  for (int r = 0; r < 4; ++r) {
    const float inv = 1.0f / lg[r];
    uint2 wv;
    wv.x = cvt_pk_bf16(acc[r][0] * inv, acc[r][1] * inv);
    wv.y = cvt_pk_bf16(acc[r][2] * inv, acc[r][3] * inv);
    *(uint2*)(Y + (long)(qrow0 + rg * 4 + r) * 768 + h * 64 + dg * 4) = wv;
  }
}

extern "C" void kernel_launch(void* const* d_in, const int* in_sizes, int n_in,
                              void* d_out, int out_size, void* d_ws, size_t ws_size,
                              hipStream_t stream) {
  const float* x      = (const float*)d_in[0];
  const float* w_attn = (const float*)d_in[1];
  const float* w_proj = (const float*)d_in[2];
  float* out = (float*)d_out;
  char* ws = (char*)d_ws;

  ushort* xb   = (ushort*)(ws);                 // 4096*768
  ushort* wAb  = (ushort*)(ws + 6291456);       // 2304*768
  ushort* wPb  = (ushort*)(ws + 9830400);       // 768*768
  float*  cosT = (float*)(ws + 11010048);       // 4096*32
  float*  sinT = (float*)(ws + 11534336);
  char*   partR = (ws + 12058624);              // flash split-K partials (compact, 30.1MB)
  ushort* Qb   = (ushort*)(ws + 49807360);      // [12][4096][64]
  ushort* Kbb  = (ushort*)(ws + 56098816);
  ushort* Vt   = (ushort*)(ws + 62390272);      // [12][64][4096]
  ushort* Yb   = (ushort*)(ws + 68681728);      // [4096][768]

  prep_all<<<2752, 256, 0, stream>>>(x, w_attn, w_proj, xb, wAb, wPb, cosT, sinT);
  gemm_qkv<<<576, 256, 0, stream>>>(xb, wAb, cosT, sinT, Qb, Kbb, Vt);
  flash_attn<<<1728, 512, 0, stream>>>(Qb, Kbb, Vt, partR);
  flash_combine<<<dim3(256, NH), 64, 0, stream>>>(partR, Yb);
  gemm_bt<<<192, 256, 0, stream>>>(Yb, wPb, out, 4096, 768, 768);
}

// Round 21
// 104.199 us; speedup vs baseline: 1.2979x; 1.0302x over previous
//
#include <hip/hip_runtime.h>
#include <hip/hip_bf16.h>
#include <stdint.h>

#define T_SEQ 4096
#define NH 12

#if __has_builtin(__builtin_amdgcn_exp2f)
#define EXP2F __builtin_amdgcn_exp2f
#else
#define EXP2F exp2f
#endif

typedef __attribute__((ext_vector_type(4))) float f32x4;
typedef __attribute__((ext_vector_type(8))) __bf16 bf16x8;

__device__ inline ushort f2b(float f) {
  __hip_bfloat16 h = __float2bfloat16(f);
  return *reinterpret_cast<ushort*>(&h);
}
__device__ inline float b2f(ushort u) {
  union { uint i; float f; } v; v.i = (uint)u << 16; return v.f;
}
// one-instruction packed f32x2 -> bf16x2 (operand order proven by r17)
__device__ inline uint cvt_pk_bf16(float a, float b) {
  uint r;
  asm("v_cvt_pk_bf16_f32 %0, %1, %2" : "=v"(r) : "v"(a), "v"(b));
  return r;
}
__device__ inline float max3f(float a, float b, float c) {
  return fmaxf(fmaxf(a, b), c);   // clang fuses to v_max3_f32
}

__device__ inline void gload_lds16(const void* g, void* lds) {
  auto g1 = (const __attribute__((address_space(1))) uint32_t*)(uintptr_t)g;
  auto l3 = (__attribute__((address_space(3))) uint32_t*)(uintptr_t)lds;
  __builtin_amdgcn_global_load_lds(g1, l3, 16, 0, 0);
}

// ---------------- fused prep: 3x fp32->bf16 convert + RoPE tables, one launch ----------------
__global__ __launch_bounds__(256) void prep_all(const float* __restrict__ x,
                                                const float* __restrict__ wA,
                                                const float* __restrict__ wP,
                                                ushort* __restrict__ xb,
                                                ushort* __restrict__ wAb,
                                                ushort* __restrict__ wPb,
                                                float* __restrict__ cosT,
                                                float* __restrict__ sinT) {
  const int u = blockIdx.x * blockDim.x + threadIdx.x;
  if (u < 688128) {
    const float* src;
    ushort* dst;
    long i;
    if (u < 393216)      { src = x;  dst = xb;  i = u; }
    else if (u < 614400) { src = wA; dst = wAb; i = u - 393216; }
    else                 { src = wP; dst = wPb; i = u - 614400; }
    const float4* s4 = (const float4*)src;
    float4 a = s4[i * 2], b = s4[i * 2 + 1];
    uint4 o;
    o.x = (uint)f2b(a.x) | ((uint)f2b(a.y) << 16);
    o.y = (uint)f2b(a.z) | ((uint)f2b(a.w) << 16);
    o.z = (uint)f2b(b.x) | ((uint)f2b(b.y) << 16);
    o.w = (uint)f2b(b.z) | ((uint)f2b(b.w) << 16);
    *(uint4*)(dst + i * 8) = o;
  } else if (u < 704512) {
    const int base = (u - 688128) * 8;   // i = t*32 + d
    const int t = base >> 5;
#pragma unroll
    for (int j = 0; j < 8; ++j) {
      const int d = (base + j) & 31;
      float theta = EXP2F((float)d * (-13.28771238f / 32.0f));  // 10000^(-d/32)
      float a = (float)t * theta;
      cosT[base + j] = cosf(a);
      sinT[base + j] = sinf(a);
    }
  }
}

// ---------------- GEMM1 + fused RoPE/reorder epilogue (BK=32 dbuf: LDS 32KB -> 4 blk/CU,
// single generation for the 576-block grid; was 64KB -> 2 blk/CU -> 512 slots < 576 = tail) ----------------
__global__ __launch_bounds__(256, 4) void gemm_qkv(const ushort* __restrict__ A,
                                                   const ushort* __restrict__ B,
                                                   const float* __restrict__ cosT,
                                                   const float* __restrict__ sinT,
                                                   ushort* __restrict__ Q,
                                                   ushort* __restrict__ Kb,
                                                   ushort* __restrict__ Vt) {
  __shared__ ushort As[2][4096];   // [128 rows][32]
  __shared__ ushort Bs[2][4096];
  const int wg = (blockIdx.x & 7) * 72 + (blockIdx.x >> 3);
  const int bx = wg % 18;
  const int by = wg / 18;
  const int t = threadIdx.x;
  const int w = t >> 6, l = t & 63;
  const int lo = l & 15, hi = l >> 4;
  const int wr = w >> 1, wc = w & 1;
  const long arow = (long)by * 128;
  const long brow = (long)bx * 128;
  const int K = 768;
  f32x4 acc[4][4] = {};

#define GSTAGE(bufg, k0s)                                                       \
  {                                                                             \
    _Pragma("unroll")                                                           \
    for (int i_ = 0; i_ < 2; ++i_) {                                            \
      int e_ = i_ * 2048 + t * 8;                                               \
      int r_ = e_ >> 5, c_ = e_ & 31;                                           \
      gload_lds16(A + (arow + r_) * (long)K + (k0s) + c_,                       \
                  (char*)&As[bufg][0] + i_ * 4096 + w * 1024);                  \
      gload_lds16(B + (brow + r_) * (long)K + (k0s) + c_,                       \
                  (char*)&Bs[bufg][0] + i_ * 4096 + w * 1024);                  \
    }                                                                           \
  }

  GSTAGE(0, 0);
  __syncthreads();
  int bufg = 0;
  for (int k0 = 0; k0 < K; k0 += 32) {
    if (k0 + 32 < K) GSTAGE(bufg ^ 1, k0 + 32);
    {
      bf16x8 af[4], bfr[4];
      for (int m = 0; m < 4; ++m)
        af[m] = *(const bf16x8*)&As[bufg][(wr * 64 + m * 16 + lo) * 32 + hi * 8];
      for (int n = 0; n < 4; ++n)
        bfr[n] = *(const bf16x8*)&Bs[bufg][(wc * 64 + n * 16 + lo) * 32 + hi * 8];
      for (int m = 0; m < 4; ++m)
        for (int n = 0; n < 4; ++n)
          acc[m][n] = __builtin_amdgcn_mfma_f32_16x16x32_bf16(af[m], bfr[n], acc[m][n], 0, 0, 0);
    }
    __syncthreads();
    bufg ^= 1;
  }
#undef GSTAGE
  // ---- fused epilogue ----
  const int rq = bx / 6;                 // 0=Q, 1=K, 2=V
  const int h  = (bx % 6) * 2 + wc;      // head for this thread's cols
  const long hT = (long)h * T_SEQ;
  if (rq < 2) {
    ushort* dst = (rq == 0) ? Q : Kb;
    const float qsc = (rq == 0) ? 0.125f * 1.44269504f : 1.0f;
#pragma unroll
    for (int m = 0; m < 4; ++m)
#pragma unroll
      for (int r = 0; r < 4; ++r) {
        const long trow = arow + wr * 64 + m * 16 + hi * 4 + r;
        ushort* rowp = dst + (hT + trow) * 64;
        const float* cp = cosT + trow * 32;
        const float* sp = sinT + trow * 32;
#pragma unroll
        for (int n = 0; n < 2; ++n) {
          const int dd = n * 16 + lo;
          const float cs = cp[dd], sn = sp[dd];
          const float a = acc[m][n][r], b = acc[m][n + 2][r];
          rowp[dd]      = f2b((a * cs - b * sn) * qsc);
          rowp[dd + 32] = f2b((a * sn + b * cs) * qsc);
        }
      }
  } else {
#pragma unroll
    for (int m = 0; m < 4; ++m) {
      const long trow0 = arow + wr * 64 + m * 16 + hi * 4;
#pragma unroll
      for (int n = 0; n < 4; ++n) {
        const int d = n * 16 + lo;
        uint2 pk;
        pk.x = (uint)f2b(acc[m][n][0]) | ((uint)f2b(acc[m][n][1]) << 16);
        pk.y = (uint)f2b(acc[m][n][2]) | ((uint)f2b(acc[m][n][3]) << 16);
        *(uint2*)(Vt + ((long)h * 64 + d) * T_SEQ + trow0) = pk;
      }
    }
  }
}

// ---------------- bf16 GEMM, C = A * B^T (fp32 out; out-proj; BK=64 dbuf, <=1 blk/CU so no tail) ----------------
__global__ __launch_bounds__(256) void gemm_bt(const ushort* __restrict__ A,
                                               const ushort* __restrict__ B,
                                               float* __restrict__ C,
                                               int M, int N, int K) {
  __shared__ ushort As[2][8192];
  __shared__ ushort Bs[2][8192];
  const int nbx = N >> 7;
  const int nwg = (M >> 7) * nbx;
  const int cpx = nwg >> 3;
  const int wg = (blockIdx.x & 7) * cpx + (blockIdx.x >> 3);
  const int bx = wg % nbx;
  const int by = wg / nbx;
  const int t = threadIdx.x;
  const int w = t >> 6, l = t & 63;
  const int lo = l & 15, hi = l >> 4;
  const int wr = w >> 1, wc = w & 1;
  const long arow = (long)by * 128;
  const long brow = (long)bx * 128;
  f32x4 acc[4][4] = {};

#define GSTAGE(bufg, k0s)                                                       \
  {                                                                             \
    _Pragma("unroll")                                                           \
    for (int i_ = 0; i_ < 4; ++i_) {                                            \
      int e_ = i_ * 2048 + t * 8;                                               \
      int r_ = e_ >> 6, c_ = e_ & 63;                                           \
      gload_lds16(A + (arow + r_) * (long)K + (k0s) + c_,                       \
                  (char*)&As[bufg][0] + i_ * 4096 + w * 1024);                  \
      gload_lds16(B + (brow + r_) * (long)K + (k0s) + c_,                       \
                  (char*)&Bs[bufg][0] + i_ * 4096 + w * 1024);                  \
    }                                                                           \
  }

  GSTAGE(0, 0);
  __syncthreads();
  int bufg = 0;
  for (int k0 = 0; k0 < K; k0 += 64) {
    if (k0 + 64 < K) GSTAGE(bufg ^ 1, k0 + 64);
    for (int kk = 0; kk < 2; ++kk) {
      bf16x8 af[4], bfr[4];
      for (int m = 0; m < 4; ++m)
        af[m] = *(const bf16x8*)&As[bufg][(wr * 64 + m * 16 + lo) * 64 + kk * 32 + hi * 8];
      for (int n = 0; n < 4; ++n)
        bfr[n] = *(const bf16x8*)&Bs[bufg][(wc * 64 + n * 16 + lo) * 64 + kk * 32 + hi * 8];
      for (int m = 0; m < 4; ++m)
        for (int n = 0; n < 4; ++n)
          acc[m][n] = __builtin_amdgcn_mfma_f32_16x16x32_bf16(af[m], bfr[n], acc[m][n], 0, 0, 0);
    }
    __syncthreads();
    bufg ^= 1;
  }
#undef GSTAGE
  for (int m = 0; m < 4; ++m) {
    long row0 = arow + wr * 64 + m * 16 + hi * 4;
    for (int n = 0; n < 4; ++n) {
      long col = brow + wc * 64 + n * 16 + lo;
      for (int r = 0; r < 4; ++r)
        C[(row0 + r) * (long)N + col] = acc[m][n][r];
    }
  }
}

// ---------------- flash attention: 8-wave blocks, 512-key chunks, permuted-K, no P-LDS ----------------
// r19 state (known-good, 52us): cvt_pk pack, max3 tree, scalar lsum, no unroll pragma.
// K rows staged PERMUTED (pi) so each lane's softmax outputs ARE its PV A-fragment.
// Causal key: k0 + (kt>>1)*32 + (kt&1)*4 + hi*8 + r.
__global__ __launch_bounds__(512, 4) void flash_attn(const ushort* __restrict__ Q,
                                                     const ushort* __restrict__ Kb,
                                                     const ushort* __restrict__ Vt,
                                                     char* __restrict__ part) {
  const int n    = blockIdx.x;
  const int slot = n >> 3;
  const int u    = slot / 72;                       // unit slot within XCD (0..2)
  int b          = slot - u * 72;                   // block index within unit
  const int unit = (n & 7) * 3 + u;                 // 0..23
  const int h    = unit >> 1;
  const int par  = unit & 1;
  const int top  = par ? 31 : 30;
  int qb = 0, cc = 0;
#pragma unroll 1
  for (int j = 0; j < 16; ++j) {                    // decode b -> (qb, cc), longest-qb first
    int q = top - 2 * j;
    int nc = (q >> 2) + 1;
    if (b < nc) { qb = q; cc = b; break; }
    b -= nc;
  }
  const int kstart  = cc << 9;
  const int blk_lim = qb * 128 + 128;
  const int kend = (kstart + 512 < blk_lim) ? kstart + 512 : blk_lim;

  __shared__ ushort Ks[2][4096];   // [64 rows][64 bf16], rows key-permuted, chunks XOR-swizzled
  __shared__ ushort Vs[2][4096];

  const int t = threadIdx.x;
  const int w = t >> 6, l = t & 63;
  const int lo = l & 15, hi = l >> 4, lo7 = l & 7;
  const int qrow0 = qb * 128 + w * 16;
  const int qlim  = qrow0 + 16;
  const int qabs  = qrow0 + lo;
  const long hT   = (long)h * T_SEQ;
  const long hT64 = (long)h * 64;

  const int srow8 = l >> 3;               // 0..7: row within this wave's 8-row group
  const int row_w = w * 8 + srow8;        // 0..63: LDS tile row this lane stages
  const int prow  = ((row_w >> 5) & 1) * 32 + ((row_w >> 2) & 3) * 8 +
                    ((row_w >> 4) & 1) * 4 + (row_w & 3);   // pi(row_w): source K key
  const int schk  = (l & 7) ^ srow8;      // inverse-swizzled source 16B-chunk

  bf16x8 qf0, qf1;
  {
    const ushort* qp = Q + (hT + qrow0 + lo) * 64 + hi * 8;
    qf0 = *(const bf16x8*)qp;
    qf1 = *(const bf16x8*)(qp + 32);
  }
  f32x4 o[4] = {};
  float m = -1e30f, lsum = 0.0f;

#define STAGE(buf, k0s)                                                         \
  {                                                                             \
    gload_lds16(Kb + (hT + (k0s) + prow) * 64 + schk * 8,                       \
                (char*)&Ks[buf][0] + w * 1024);                                 \
    gload_lds16(Vt + (hT64 + row_w) * T_SEQ + (k0s) + schk * 8,                 \
                (char*)&Vs[buf][0] + w * 1024);                                 \
  }

  STAGE(0, kstart);
  __syncthreads();
  int buf = 0;

  for (int k0 = kstart; k0 < kend; k0 += 64) {
    if (k0 + 64 < kend) STAGE(buf ^ 1, k0 + 64);
    if (k0 < qlim) {
      const ushort* kt_ = &Ks[buf][0];
      const ushort* vt_ = &Vs[buf][0];
      // --- S^T = K . Q^T from swizzled LDS (rows key-permuted) ---
      f32x4 s[4];
      __builtin_amdgcn_s_setprio(1);
#pragma unroll
      for (int kt = 0; kt < 4; ++kt) {
        int rr = kt * 16 + lo;
        bf16x8 ka = *(const bf16x8*)(kt_ + rr * 64 + ((hi ^ lo7) * 8));
        bf16x8 kc = *(const bf16x8*)(kt_ + rr * 64 + (((4 + hi) ^ lo7) * 8));
        f32x4 a = {};
        a = __builtin_amdgcn_mfma_f32_16x16x32_bf16(ka, qf0, a, 0, 0, 0);
        a = __builtin_amdgcn_mfma_f32_16x16x32_bf16(kc, qf1, a, 0, 0, 0);
        s[kt] = a;
      }
      __builtin_amdgcn_s_setprio(0);
      // --- V fragments early (latency overlaps softmax) ---
      bf16x8 vf[8];
#pragma unroll
      for (int dt = 0; dt < 4; ++dt)
#pragma unroll
        for (int cv = 0; cv < 2; ++cv) {
          int rr = dt * 16 + lo;
          vf[dt * 2 + cv] = *(const bf16x8*)(vt_ + rr * 64 + (((cv * 4 + hi) ^ lo7) * 8));
        }
      // --- causal mask (diagonal tiles only); key honors the row permutation ---
      if (k0 + 64 > qrow0) {
#pragma unroll
        for (int kt = 0; kt < 4; ++kt) {
          const int bkt = (kt >> 1) * 32 + (kt & 1) * 4;
#pragma unroll
          for (int r = 0; r < 4; ++r) {
            int key = k0 + bkt + hi * 8 + r;
            if (key > qabs) s[kt][r] = -1e30f;
          }
        }
      }
      // --- row max: max3 tree + 2 shfl ---
      float m1 = max3f(s[0][0], s[0][1], s[0][2]);
      float m2 = max3f(s[0][3], s[1][0], s[1][1]);
      float m3 = max3f(s[1][2], s[1][3], s[2][0]);
      float m4 = max3f(s[2][1], s[2][2], s[2][3]);
      float m5 = max3f(s[3][0], s[3][1], s[3][2]);
      float mt = max3f(max3f(m1, m2, m3), max3f(m4, m5, s[3][3]), -1e30f);
      mt = fmaxf(mt, __shfl_xor(mt, 16));
      mt = fmaxf(mt, __shfl_xor(mt, 32));
      // --- defer-max rescale (THR=8 in log2 domain) ---
      if (!__all(mt - m <= 8.0f)) {
        float mn = fmaxf(m, mt);
        float alpha = EXP2F(m - mn);
        m = mn;
        lsum *= alpha;
#pragma unroll
        for (int r = 0; r < 4; ++r) {
          float ar = __shfl(alpha, hi * 4 + r);
#pragma unroll
          for (int dt = 0; dt < 4; ++dt) o[dt][r] *= ar;
        }
      }
      // --- exp2 + per-lane sum + pack P via v_cvt_pk_bf16_f32 ---
      uint us[8];
#pragma unroll
      for (int kt = 0; kt < 4; ++kt) {
        float p0 = EXP2F(s[kt][0] - m);
        float p1 = EXP2F(s[kt][1] - m);
        float p2 = EXP2F(s[kt][2] - m);
        float p3 = EXP2F(s[kt][3] - m);
        lsum += (p0 + p1) + (p2 + p3);
        us[kt * 2]     = cvt_pk_bf16(p0, p1);
        us[kt * 2 + 1] = cvt_pk_bf16(p2, p3);
      }
      // --- PV: A-fragment is a pure register reassembly ---
      __builtin_amdgcn_s_setprio(1);
#pragma unroll
      for (int cv = 0; cv < 2; ++cv) {
        union { uint4 q; bf16x8 v; } pc;
        pc.q.x = us[cv * 4 + 0];
        pc.q.y = us[cv * 4 + 1];
        pc.q.z = us[cv * 4 + 2];
        pc.q.w = us[cv * 4 + 3];
#pragma unroll
        for (int dt = 0; dt < 4; ++dt)
          o[dt] = __builtin_amdgcn_mfma_f32_16x16x32_bf16(pc.v, vf[dt * 2 + cv], o[dt], 0, 0, 0);
      }
      __builtin_amdgcn_s_setprio(0);
    }
    __syncthreads();
    buf ^= 1;
  }
#undef STAGE

  // --- write partial (unnormalized); compact prefix-indexed slot ---
  if (kstart < qlim) {
    lsum += __shfl_xor(lsum, 16);
    lsum += __shfl_xor(lsum, 32);
    const int g  = qb >> 2;
    const int rr = 8 * (qb & 3) + w;
    const long slotp = (long)h * 1152 + 16 * g * (g + 1) + rr * (g + 1) + cc;
    char* pb = part + slotp * 2176;
    ushort* po = (ushort*)pb;
#pragma unroll
    for (int dt = 0; dt < 4; ++dt)
#pragma unroll
      for (int r = 0; r < 4; ++r)
        po[(hi * 4 + r) * 64 + dt * 16 + lo] = f2b(o[dt][r]);
    if (hi == 0) {
      ((float*)(pb + 2048))[lo] = m;
      ((float*)(pb + 2112))[lo] = lsum;
    }
  }
}

// ---------------- split-K combine (vectorized: 4 rows x 4 cols per thread, ushort4 loads) ----------------
__global__ __launch_bounds__(64) void flash_combine(const char* __restrict__ part,
                                                    ushort* __restrict__ Y) {
  const int qg = blockIdx.x, h = blockIdx.y;
  const int dg = threadIdx.x & 15;       // 4-col group: cols dg*4 .. dg*4+3
  const int rg = threadIdx.x >> 4;       // 4-row group: rows rg*4 .. rg*4+3
  const int qrow0 = qg * 16;
  const int g = qg >> 5, rr = qg & 31;
  const int nch = g + 1;
  const char* ub = part + ((long)h * 1152 + 16 * g * (g + 1) + (long)rr * (g + 1)) * 2176;
  float Mg[4];
#pragma unroll
  for (int r = 0; r < 4; ++r) Mg[r] = -1e30f;
  for (int cc = 0; cc < nch; ++cc) {
    const float* mp = (const float*)(ub + cc * 2176 + 2048);
#pragma unroll
    for (int r = 0; r < 4; ++r) Mg[r] = fmaxf(Mg[r], mp[rg * 4 + r]);
  }
  float acc[4][4] = {};
  float lg[4] = {};
  for (int cc = 0; cc < nch; ++cc) {
    const ushort* op = (const ushort*)(ub + cc * 2176);
    const float* mp = (const float*)(ub + cc * 2176 + 2048);
    const float* lp = (const float*)(ub + cc * 2176 + 2112);
#pragma unroll
    for (int r = 0; r < 4; ++r) {
      const int ra = rg * 4 + r;
      float wgt = EXP2F(mp[ra] - Mg[r]);
      ushort4 v = *(const ushort4*)(op + ra * 64 + dg * 4);
      acc[r][0] += wgt * b2f(v.x);
      acc[r][1] += wgt * b2f(v.y);
      acc[r][2] += wgt * b2f(v.z);
      acc[r][3] += wgt * b2f(v.w);
      lg[r] += wgt * lp[ra];
    }
  }
#pragma unroll
  for (int r = 0; r < 4; ++r) {
    const float inv = 1.0f / lg[r];
    uint2 wv;
    wv.x = cvt_pk_bf16(acc[r][0] * inv, acc[r][1] * inv);
    wv.y = cvt_pk_bf16(acc[r][2] * inv, acc[r][3] * inv);
    *(uint2*)(Y + (long)(qrow0 + rg * 4 + r) * 768 + h * 64 + dg * 4) = wv;
  }
}

extern "C" void kernel_launch(void* const* d_in, const int* in_sizes, int n_in,
                              void* d_out, int out_size, void* d_ws, size_t ws_size,
                              hipStream_t stream) {
  const float* x      = (const float*)d_in[0];
  const float* w_attn = (const float*)d_in[1];
  const float* w_proj = (const float*)d_in[2];
  float* out = (float*)d_out;
  char* ws = (char*)d_ws;

  ushort* xb   = (ushort*)(ws);                 // 4096*768
  ushort* wAb  = (ushort*)(ws + 6291456);       // 2304*768
  ushort* wPb  = (ushort*)(ws + 9830400);       // 768*768
  float*  cosT = (float*)(ws + 11010048);       // 4096*32
  float*  sinT = (float*)(ws + 11534336);
  char*   partR = (ws + 12058624);              // flash split-K partials (compact, 30.1MB)
  ushort* Qb   = (ushort*)(ws + 49807360);      // [12][4096][64]
  ushort* Kbb  = (ushort*)(ws + 56098816);
  ushort* Vt   = (ushort*)(ws + 62390272);      // [12][64][4096]
  ushort* Yb   = (ushort*)(ws + 68681728);      // [4096][768]

  prep_all<<<2752, 256, 0, stream>>>(x, w_attn, w_proj, xb, wAb, wPb, cosT, sinT);
  gemm_qkv<<<576, 256, 0, stream>>>(xb, wAb, cosT, sinT, Qb, Kbb, Vt);
  flash_attn<<<1728, 512, 0, stream>>>(Qb, Kbb, Vt, partR);
  flash_combine<<<dim3(256, NH), 64, 0, stream>>>(partR, Yb);
  gemm_bt<<<192, 256, 0, stream>>>(Yb, wPb, out, 4096, 768, 768);
}

// Round 24
// 103.040 us; speedup vs baseline: 1.3125x; 1.0112x over previous
//
#include <hip/hip_runtime.h>
#include <hip/hip_bf16.h>
#include <stdint.h>

#define T_SEQ 4096
#define NH 12

#if __has_builtin(__builtin_amdgcn_exp2f)
#define EXP2F __builtin_amdgcn_exp2f
#else
#define EXP2F exp2f
#endif

typedef __attribute__((ext_vector_type(4))) float f32x4;
typedef __attribute__((ext_vector_type(8))) __bf16 bf16x8;

__device__ inline ushort f2b(float f) {
  __hip_bfloat16 h = __float2bfloat16(f);
  return *reinterpret_cast<ushort*>(&h);
}
__device__ inline float b2f(ushort u) {
  union { uint i; float f; } v; v.i = (uint)u << 16; return v.f;
}
__device__ inline float b2f_lo(uint u) {   // low ushort of a packed pair -> float
  union { uint i; float f; } v; v.i = u << 16; return v.f;
}
__device__ inline float b2f_hi(uint u) {   // high ushort -> float (just mask)
  union { uint i; float f; } v; v.i = u & 0xffff0000u; return v.f;
}
// one-instruction packed f32x2 -> bf16x2 (operand order proven by r17)
__device__ inline uint cvt_pk_bf16(float a, float b) {
  uint r;
  asm("v_cvt_pk_bf16_f32 %0, %1, %2" : "=v"(r) : "v"(a), "v"(b));
  return r;
}
__device__ inline float max3f(float a, float b, float c) {
  return fmaxf(fmaxf(a, b), c);   // clang fuses to v_max3_f32
}

__device__ inline void gload_lds16(const void* g, void* lds) {
  auto g1 = (const __attribute__((address_space(1))) uint32_t*)(uintptr_t)g;
  auto l3 = (__attribute__((address_space(3))) uint32_t*)(uintptr_t)lds;
  __builtin_amdgcn_global_load_lds(g1, l3, 16, 0, 0);
}

// ---------------- fused prep: 3x fp32->bf16 convert + RoPE tables, one launch ----------------
__global__ __launch_bounds__(256) void prep_all(const float* __restrict__ x,
                                                const float* __restrict__ wA,
                                                const float* __restrict__ wP,
                                                ushort* __restrict__ xb,
                                                ushort* __restrict__ wAb,
                                                ushort* __restrict__ wPb,
                                                float* __restrict__ cosT,
                                                float* __restrict__ sinT) {
  const int u = blockIdx.x * blockDim.x + threadIdx.x;
  if (u < 688128) {
    const float* src;
    ushort* dst;
    long i;
    if (u < 393216)      { src = x;  dst = xb;  i = u; }
    else if (u < 614400) { src = wA; dst = wAb; i = u - 393216; }
    else                 { src = wP; dst = wPb; i = u - 614400; }
    const float4* s4 = (const float4*)src;
    float4 a = s4[i * 2], b = s4[i * 2 + 1];
    uint4 o;
    o.x = (uint)f2b(a.x) | ((uint)f2b(a.y) << 16);
    o.y = (uint)f2b(a.z) | ((uint)f2b(a.w) << 16);
    o.z = (uint)f2b(b.x) | ((uint)f2b(b.y) << 16);
    o.w = (uint)f2b(b.z) | ((uint)f2b(b.w) << 16);
    *(uint4*)(dst + i * 8) = o;
  } else if (u < 704512) {
    const int base = (u - 688128) * 8;   // i = t*32 + d
    const int t = base >> 5;
#pragma unroll
    for (int j = 0; j < 8; ++j) {
      const int d = (base + j) & 31;
      float theta = EXP2F((float)d * (-13.28771238f / 32.0f));  // 10000^(-d/32)
      float a = (float)t * theta;
      cosT[base + j] = cosf(a);
      sinT[base + j] = sinf(a);
    }
  }
}

// ---------------- GEMM1 + fused RoPE/reorder epilogue (BK=32 dbuf: LDS 32KB -> 4 blk/CU) ----------------
__global__ __launch_bounds__(256, 4) void gemm_qkv(const ushort* __restrict__ A,
                                                   const ushort* __restrict__ B,
                                                   const float* __restrict__ cosT,
                                                   const float* __restrict__ sinT,
                                                   ushort* __restrict__ Q,
                                                   ushort* __restrict__ Kb,
                                                   ushort* __restrict__ Vt) {
  __shared__ ushort As[2][4096];   // [128 rows][32]
  __shared__ ushort Bs[2][4096];
  const int wg = (blockIdx.x & 7) * 72 + (blockIdx.x >> 3);
  const int bx = wg % 18;
  const int by = wg / 18;
  const int t = threadIdx.x;
  const int w = t >> 6, l = t & 63;
  const int lo = l & 15, hi = l >> 4;
  const int wr = w >> 1, wc = w & 1;
  const long arow = (long)by * 128;
  const long brow = (long)bx * 128;
  const int K = 768;
  f32x4 acc[4][4] = {};

#define GSTAGE(bufg, k0s)                                                       \
  {                                                                             \
    _Pragma("unroll")                                                           \
    for (int i_ = 0; i_ < 2; ++i_) {                                            \
      int e_ = i_ * 2048 + t * 8;                                               \
      int r_ = e_ >> 5, c_ = e_ & 31;                                           \
      gload_lds16(A + (arow + r_) * (long)K + (k0s) + c_,                       \
                  (char*)&As[bufg][0] + i_ * 4096 + w * 1024);                  \
      gload_lds16(B + (brow + r_) * (long)K + (k0s) + c_,                       \
                  (char*)&Bs[bufg][0] + i_ * 4096 + w * 1024);                  \
    }                                                                           \
  }

  GSTAGE(0, 0);
  __syncthreads();
  int bufg = 0;
  for (int k0 = 0; k0 < K; k0 += 32) {
    if (k0 + 32 < K) GSTAGE(bufg ^ 1, k0 + 32);
    {
      bf16x8 af[4], bfr[4];
      for (int m = 0; m < 4; ++m)
        af[m] = *(const bf16x8*)&As[bufg][(wr * 64 + m * 16 + lo) * 32 + hi * 8];
      for (int n = 0; n < 4; ++n)
        bfr[n] = *(const bf16x8*)&Bs[bufg][(wc * 64 + n * 16 + lo) * 32 + hi * 8];
      for (int m = 0; m < 4; ++m)
        for (int n = 0; n < 4; ++n)
          acc[m][n] = __builtin_amdgcn_mfma_f32_16x16x32_bf16(af[m], bfr[n], acc[m][n], 0, 0, 0);
    }
    __syncthreads();
    bufg ^= 1;
  }
#undef GSTAGE
  // ---- fused epilogue ----
  const int rq = bx / 6;                 // 0=Q, 1=K, 2=V
  const int h  = (bx % 6) * 2 + wc;      // head for this thread's cols
  const long hT = (long)h * T_SEQ;
  if (rq < 2) {
    ushort* dst = (rq == 0) ? Q : Kb;
    const float qsc = (rq == 0) ? 0.125f * 1.44269504f : 1.0f;
#pragma unroll
    for (int m = 0; m < 4; ++m)
#pragma unroll
      for (int r = 0; r < 4; ++r) {
        const long trow = arow + wr * 64 + m * 16 + hi * 4 + r;
        ushort* rowp = dst + (hT + trow) * 64;
        const float* cp = cosT + trow * 32;
        const float* sp = sinT + trow * 32;
#pragma unroll
        for (int n = 0; n < 2; ++n) {
          const int dd = n * 16 + lo;
          const float cs = cp[dd], sn = sp[dd];
          const float a = acc[m][n][r], b = acc[m][n + 2][r];
          rowp[dd]      = f2b((a * cs - b * sn) * qsc);
          rowp[dd + 32] = f2b((a * sn + b * cs) * qsc);
        }
      }
  } else {
#pragma unroll
    for (int m = 0; m < 4; ++m) {
      const long trow0 = arow + wr * 64 + m * 16 + hi * 4;
#pragma unroll
      for (int n = 0; n < 4; ++n) {
        const int d = n * 16 + lo;
        uint2 pk;
        pk.x = (uint)f2b(acc[m][n][0]) | ((uint)f2b(acc[m][n][1]) << 16);
        pk.y = (uint)f2b(acc[m][n][2]) | ((uint)f2b(acc[m][n][3]) << 16);
        *(uint2*)(Vt + ((long)h * 64 + d) * T_SEQ + trow0) = pk;
      }
    }
  }
}

// ---------------- bf16 GEMM, C = A * B^T (fp32 out; out-proj; BK=64 dbuf) ----------------
__global__ __launch_bounds__(256) void gemm_bt(const ushort* __restrict__ A,
                                               const ushort* __restrict__ B,
                                               float* __restrict__ C,
                                               int M, int N, int K) {
  __shared__ ushort As[2][8192];
  __shared__ ushort Bs[2][8192];
  const int nbx = N >> 7;
  const int nwg = (M >> 7) * nbx;
  const int cpx = nwg >> 3;
  const int wg = (blockIdx.x & 7) * cpx + (blockIdx.x >> 3);
  const int bx = wg % nbx;
  const int by = wg / nbx;
  const int t = threadIdx.x;
  const int w = t >> 6, l = t & 63;
  const int lo = l & 15, hi = l >> 4;
  const int wr = w >> 1, wc = w & 1;
  const long arow = (long)by * 128;
  const long brow = (long)bx * 128;
  f32x4 acc[4][4] = {};

#define GSTAGE(bufg, k0s)                                                       \
  {                                                                             \
    _Pragma("unroll")                                                           \
    for (int i_ = 0; i_ < 4; ++i_) {                                            \
      int e_ = i_ * 2048 + t * 8;                                               \
      int r_ = e_ >> 6, c_ = e_ & 63;                                           \
      gload_lds16(A + (arow + r_) * (long)K + (k0s) + c_,                       \
                  (char*)&As[bufg][0] + i_ * 4096 + w * 1024);                  \
      gload_lds16(B + (brow + r_) * (long)K + (k0s) + c_,                       \
                  (char*)&Bs[bufg][0] + i_ * 4096 + w * 1024);                  \
    }                                                                           \
  }

  GSTAGE(0, 0);
  __syncthreads();
  int bufg = 0;
  for (int k0 = 0; k0 < K; k0 += 64) {
    if (k0 + 64 < K) GSTAGE(bufg ^ 1, k0 + 64);
    for (int kk = 0; kk < 2; ++kk) {
      bf16x8 af[4], bfr[4];
      for (int m = 0; m < 4; ++m)
        af[m] = *(const bf16x8*)&As[bufg][(wr * 64 + m * 16 + lo) * 64 + kk * 32 + hi * 8];
      for (int n = 0; n < 4; ++n)
        bfr[n] = *(const bf16x8*)&Bs[bufg][(wc * 64 + n * 16 + lo) * 64 + kk * 32 + hi * 8];
      for (int m = 0; m < 4; ++m)
        for (int n = 0; n < 4; ++n)
          acc[m][n] = __builtin_amdgcn_mfma_f32_16x16x32_bf16(af[m], bfr[n], acc[m][n], 0, 0, 0);
    }
    __syncthreads();
    bufg ^= 1;
  }
#undef GSTAGE
  for (int m = 0; m < 4; ++m) {
    long row0 = arow + wr * 64 + m * 16 + hi * 4;
    for (int n = 0; n < 4; ++n) {
      long col = brow + wc * 64 + n * 16 + lo;
      for (int r = 0; r < 4; ++r)
        C[(row0 + r) * (long)N + col] = acc[m][n][r];
    }
  }
}

// ---------------- flash attention: 8-wave blocks, 512-key chunks, permuted-K, no P-LDS ----------------
// r21-passing form (scalar lsum). o_sum-via-MFMA is PERMANENTLY DROPPED: r18 and r23 both
// failed with bit-identical absmax 1.3245 -- deterministic breakage attributable to that
// change alone despite the fragment algebra reading correct.
// K rows staged PERMUTED (pi) so each lane's softmax outputs ARE its PV A-fragment.
// Causal key: k0 + (kt>>1)*32 + (kt&1)*4 + hi*8 + r.
__global__ __launch_bounds__(512, 4) void flash_attn(const ushort* __restrict__ Q,
                                                     const ushort* __restrict__ Kb,
                                                     const ushort* __restrict__ Vt,
                                                     char* __restrict__ part) {
  const int n    = blockIdx.x;
  const int slot = n >> 3;
  const int u    = slot / 72;                       // unit slot within XCD (0..2)
  int b          = slot - u * 72;                   // block index within unit
  const int unit = (n & 7) * 3 + u;                 // 0..23
  const int h    = unit >> 1;
  const int par  = unit & 1;
  const int top  = par ? 31 : 30;
  int qb = 0, cc = 0;
#pragma unroll 1
  for (int j = 0; j < 16; ++j) {                    // decode b -> (qb, cc), longest-qb first
    int q = top - 2 * j;
    int nc = (q >> 2) + 1;
    if (b < nc) { qb = q; cc = b; break; }
    b -= nc;
  }
  const int kstart  = cc << 9;
  const int blk_lim = qb * 128 + 128;
  const int kend = (kstart + 512 < blk_lim) ? kstart + 512 : blk_lim;

  __shared__ ushort Ks[2][4096];   // [64 rows][64 bf16], rows key-permuted, chunks XOR-swizzled
  __shared__ ushort Vs[2][4096];

  const int t = threadIdx.x;
  const int w = t >> 6, l = t & 63;
  const int lo = l & 15, hi = l >> 4, lo7 = l & 7;
  const int qrow0 = qb * 128 + w * 16;
  const int qlim  = qrow0 + 16;
  const int qabs  = qrow0 + lo;
  const long hT   = (long)h * T_SEQ;
  const long hT64 = (long)h * 64;

  const int srow8 = l >> 3;               // 0..7: row within this wave's 8-row group
  const int row_w = w * 8 + srow8;        // 0..63: LDS tile row this lane stages
  const int prow  = ((row_w >> 5) & 1) * 32 + ((row_w >> 2) & 3) * 8 +
                    ((row_w >> 4) & 1) * 4 + (row_w & 3);   // pi(row_w): source K key
  const int schk  = (l & 7) ^ srow8;      // inverse-swizzled source 16B-chunk

  bf16x8 qf0, qf1;
  {
    const ushort* qp = Q + (hT + qrow0 + lo) * 64 + hi * 8;
    qf0 = *(const bf16x8*)qp;
    qf1 = *(const bf16x8*)(qp + 32);
  }
  f32x4 o[4] = {};
  float m = -1e30f, lsum = 0.0f;

#define STAGE(buf, k0s)                                                         \
  {                                                                             \
    gload_lds16(Kb + (hT + (k0s) + prow) * 64 + schk * 8,                       \
                (char*)&Ks[buf][0] + w * 1024);                                 \
    gload_lds16(Vt + (hT64 + row_w) * T_SEQ + (k0s) + schk * 8,                 \
                (char*)&Vs[buf][0] + w * 1024);                                 \
  }

  STAGE(0, kstart);
  __syncthreads();
  int buf = 0;

  for (int k0 = kstart; k0 < kend; k0 += 64) {
    if (k0 + 64 < kend) STAGE(buf ^ 1, k0 + 64);
    if (k0 < qlim) {
      const ushort* kt_ = &Ks[buf][0];
      const ushort* vt_ = &Vs[buf][0];
      // --- S^T = K . Q^T from swizzled LDS (rows key-permuted) ---
      f32x4 s[4];
      __builtin_amdgcn_s_setprio(1);
#pragma unroll
      for (int kt = 0; kt < 4; ++kt) {
        int rr = kt * 16 + lo;
        bf16x8 ka = *(const bf16x8*)(kt_ + rr * 64 + ((hi ^ lo7) * 8));
        bf16x8 kc = *(const bf16x8*)(kt_ + rr * 64 + (((4 + hi) ^ lo7) * 8));
        f32x4 a = {};
        a = __builtin_amdgcn_mfma_f32_16x16x32_bf16(ka, qf0, a, 0, 0, 0);
        a = __builtin_amdgcn_mfma_f32_16x16x32_bf16(kc, qf1, a, 0, 0, 0);
        s[kt] = a;
      }
      __builtin_amdgcn_s_setprio(0);
      // --- V fragments early (latency overlaps softmax) ---
      bf16x8 vf[8];
#pragma unroll
      for (int dt = 0; dt < 4; ++dt)
#pragma unroll
        for (int cv = 0; cv < 2; ++cv) {
          int rr = dt * 16 + lo;
          vf[dt * 2 + cv] = *(const bf16x8*)(vt_ + rr * 64 + (((cv * 4 + hi) ^ lo7) * 8));
        }
      // --- causal mask (diagonal tiles only); key honors the row permutation ---
      if (k0 + 64 > qrow0) {
#pragma unroll
        for (int kt = 0; kt < 4; ++kt) {
          const int bkt = (kt >> 1) * 32 + (kt & 1) * 4;
#pragma unroll
          for (int r = 0; r < 4; ++r) {
            int key = k0 + bkt + hi * 8 + r;
            if (key > qabs) s[kt][r] = -1e30f;
          }
        }
      }
      // --- row max: max3 tree + 2 shfl ---
      float m1 = max3f(s[0][0], s[0][1], s[0][2]);
      float m2 = max3f(s[0][3], s[1][0], s[1][1]);
      float m3 = max3f(s[1][2], s[1][3], s[2][0]);
      float m4 = max3f(s[2][1], s[2][2], s[2][3]);
      float m5 = max3f(s[3][0], s[3][1], s[3][2]);
      float mt = max3f(max3f(m1, m2, m3), max3f(m4, m5, s[3][3]), -1e30f);
      mt = fmaxf(mt, __shfl_xor(mt, 16));
      mt = fmaxf(mt, __shfl_xor(mt, 32));
      // --- defer-max rescale (THR=8 in log2 domain) ---
      if (!__all(mt - m <= 8.0f)) {
        float mn = fmaxf(m, mt);
        float alpha = EXP2F(m - mn);
        m = mn;
        lsum *= alpha;
#pragma unroll
        for (int r = 0; r < 4; ++r) {
          float ar = __shfl(alpha, hi * 4 + r);
#pragma unroll
          for (int dt = 0; dt < 4; ++dt) o[dt][r] *= ar;
        }
      }
      // --- exp2 + per-lane sum + pack P via v_cvt_pk_bf16_f32 ---
      uint us[8];
#pragma unroll
      for (int kt = 0; kt < 4; ++kt) {
        float p0 = EXP2F(s[kt][0] - m);
        float p1 = EXP2F(s[kt][1] - m);
        float p2 = EXP2F(s[kt][2] - m);
        float p3 = EXP2F(s[kt][3] - m);
        lsum += (p0 + p1) + (p2 + p3);
        us[kt * 2]     = cvt_pk_bf16(p0, p1);
        us[kt * 2 + 1] = cvt_pk_bf16(p2, p3);
      }
      // --- PV: A-fragment is a pure register reassembly ---
      __builtin_amdgcn_s_setprio(1);
#pragma unroll
      for (int cv = 0; cv < 2; ++cv) {
        union { uint4 q; bf16x8 v; } pc;
        pc.q.x = us[cv * 4 + 0];
        pc.q.y = us[cv * 4 + 1];
        pc.q.z = us[cv * 4 + 2];
        pc.q.w = us[cv * 4 + 3];
#pragma unroll
        for (int dt = 0; dt < 4; ++dt)
          o[dt] = __builtin_amdgcn_mfma_f32_16x16x32_bf16(pc.v, vf[dt * 2 + cv], o[dt], 0, 0, 0);
      }
      __builtin_amdgcn_s_setprio(0);
    }
    __syncthreads();
    buf ^= 1;
  }
#undef STAGE

  // --- write partial (unnormalized); compact prefix-indexed slot ---
  if (kstart < qlim) {
    lsum += __shfl_xor(lsum, 16);
    lsum += __shfl_xor(lsum, 32);
    const int g  = qb >> 2;
    const int rr = 8 * (qb & 3) + w;
    const long slotp = (long)h * 1152 + 16 * g * (g + 1) + rr * (g + 1) + cc;
    char* pb = part + slotp * 2176;
    ushort* po = (ushort*)pb;
#pragma unroll
    for (int dt = 0; dt < 4; ++dt)
#pragma unroll
      for (int r = 0; r < 4; ++r)
        po[(hi * 4 + r) * 64 + dt * 16 + lo] = f2b(o[dt][r]);
    if (hi == 0) {
      ((float*)(pb + 2048))[lo] = m;
      ((float*)(pb + 2112))[lo] = lsum;
    }
  }
}

// ---------------- split-K combine: 256 threads, 4 qg/block, 16B loads (2 rows x 8 cols/thread) ----------------
__global__ __launch_bounds__(256) void flash_combine(const char* __restrict__ part,
                                                     ushort* __restrict__ Y) {
  const int h  = blockIdx.y;
  const int qg = blockIdx.x * 4 + (threadIdx.x >> 6);  // grid.x = 64; 4 qg never straddle a g-boundary
  const int tl = threadIdx.x & 63;
  const int dg = tl & 7;          // cols dg*8 .. dg*8+7
  const int rg = tl >> 3;         // rows rg*2, rg*2+1
  const int qrow0 = qg * 16;
  const int g = qg >> 5, rr = qg & 31;
  const int nch = g + 1;
  const char* ub = part + ((long)h * 1152 + 16 * g * (g + 1) + (long)rr * (g + 1)) * 2176;
  float Mg[2] = {-1e30f, -1e30f};
  for (int cc = 0; cc < nch; ++cc) {
    const float* mp = (const float*)(ub + cc * 2176 + 2048);
    Mg[0] = fmaxf(Mg[0], mp[rg * 2]);
    Mg[1] = fmaxf(Mg[1], mp[rg * 2 + 1]);
  }
  float acc[2][8] = {};
  float lg[2] = {};
  for (int cc = 0; cc < nch; ++cc) {
    const ushort* op = (const ushort*)(ub + cc * 2176);
    const float* mp = (const float*)(ub + cc * 2176 + 2048);
    const float* lp = (const float*)(ub + cc * 2176 + 2112);
#pragma unroll
    for (int r = 0; r < 2; ++r) {
      const int ra = rg * 2 + r;
      const float wgt = EXP2F(mp[ra] - Mg[r]);
      uint4 v = *(const uint4*)(op + ra * 64 + dg * 8);
      acc[r][0] += wgt * b2f_lo(v.x);
      acc[r][1] += wgt * b2f_hi(v.x);
      acc[r][2] += wgt * b2f_lo(v.y);
      acc[r][3] += wgt * b2f_hi(v.y);
      acc[r][4] += wgt * b2f_lo(v.z);
      acc[r][5] += wgt * b2f_hi(v.z);
      acc[r][6] += wgt * b2f_lo(v.w);
      acc[r][7] += wgt * b2f_hi(v.w);
      lg[r] += wgt * lp[ra];
    }
  }
#pragma unroll
  for (int r = 0; r < 2; ++r) {
    const float inv = 1.0f / lg[r];
    uint4 wv;
    wv.x = cvt_pk_bf16(acc[r][0] * inv, acc[r][1] * inv);
    wv.y = cvt_pk_bf16(acc[r][2] * inv, acc[r][3] * inv);
    wv.z = cvt_pk_bf16(acc[r][4] * inv, acc[r][5] * inv);
    wv.w = cvt_pk_bf16(acc[r][6] * inv, acc[r][7] * inv);
    *(uint4*)(Y + (long)(qrow0 + rg * 2 + r) * 768 + h * 64 + dg * 8) = wv;
  }
}

extern "C" void kernel_launch(void* const* d_in, const int* in_sizes, int n_in,
                              void* d_out, int out_size, void* d_ws, size_t ws_size,
                              hipStream_t stream) {
  const float* x      = (const float*)d_in[0];
  const float* w_attn = (const float*)d_in[1];
  const float* w_proj = (const float*)d_in[2];
  float* out = (float*)d_out;
  char* ws = (char*)d_ws;

  ushort* xb   = (ushort*)(ws);                 // 4096*768
  ushort* wAb  = (ushort*)(ws + 6291456);       // 2304*768
  ushort* wPb  = (ushort*)(ws + 9830400);       // 768*768
  float*  cosT = (float*)(ws + 11010048);       // 4096*32
  float*  sinT = (float*)(ws + 11534336);
  char*   partR = (ws + 12058624);              // flash split-K partials (compact, 30.1MB)
  ushort* Qb   = (ushort*)(ws + 49807360);      // [12][4096][64]
  ushort* Kbb  = (ushort*)(ws + 56098816);
  ushort* Vt   = (ushort*)(ws + 62390272);      // [12][64][4096]
  ushort* Yb   = (ushort*)(ws + 68681728);      // [4096][768]

  prep_all<<<2752, 256, 0, stream>>>(x, w_attn, w_proj, xb, wAb, wPb, cosT, sinT);
  gemm_qkv<<<576, 256, 0, stream>>>(xb, wAb, cosT, sinT, Qb, Kbb, Vt);
  flash_attn<<<1728, 512, 0, stream>>>(Qb, Kbb, Vt, partR);
  flash_combine<<<dim3(64, NH), 256, 0, stream>>>(partR, Yb);
  gemm_bt<<<192, 256, 0, stream>>>(Yb, wPb, out, 4096, 768, 768);
}

// Round 25
// 100.167 us; speedup vs baseline: 1.3502x; 1.0287x over previous
//
#include <hip/hip_runtime.h>
#include <hip/hip_bf16.h>
#include <stdint.h>

#define T_SEQ 4096
#define NH 12

#if __has_builtin(__builtin_amdgcn_exp2f)
#define EXP2F __builtin_amdgcn_exp2f
#else
#define EXP2F exp2f
#endif

typedef __attribute__((ext_vector_type(4))) float f32x4;
typedef __attribute__((ext_vector_type(8))) __bf16 bf16x8;

__device__ inline ushort f2b(float f) {
  __hip_bfloat16 h = __float2bfloat16(f);
  return *reinterpret_cast<ushort*>(&h);
}
__device__ inline float b2f(ushort u) {
  union { uint i; float f; } v; v.i = (uint)u << 16; return v.f;
}
__device__ inline float b2f_lo(uint u) {   // low ushort of a packed pair -> float
  union { uint i; float f; } v; v.i = u << 16; return v.f;
}
__device__ inline float b2f_hi(uint u) {   // high ushort -> float (just mask)
  union { uint i; float f; } v; v.i = u & 0xffff0000u; return v.f;
}
// one-instruction packed f32x2 -> bf16x2 (operand order proven by r17)
__device__ inline uint cvt_pk_bf16(float a, float b) {
  uint r;
  asm("v_cvt_pk_bf16_f32 %0, %1, %2" : "=v"(r) : "v"(a), "v"(b));
  return r;
}
__device__ inline float max3f(float a, float b, float c) {
  return fmaxf(fmaxf(a, b), c);   // clang fuses to v_max3_f32
}

__device__ inline void gload_lds16(const void* g, void* lds) {
  auto g1 = (const __attribute__((address_space(1))) uint32_t*)(uintptr_t)g;
  auto l3 = (__attribute__((address_space(3))) uint32_t*)(uintptr_t)lds;
  __builtin_amdgcn_global_load_lds(g1, l3, 16, 0, 0);
}

// ---------------- fused prep: 3x fp32->bf16 convert + RoPE tables, one launch ----------------
__global__ __launch_bounds__(256) void prep_all(const float* __restrict__ x,
                                                const float* __restrict__ wA,
                                                const float* __restrict__ wP,
                                                ushort* __restrict__ xb,
                                                ushort* __restrict__ wAb,
                                                ushort* __restrict__ wPb,
                                                float* __restrict__ cosT,
                                                float* __restrict__ sinT) {
  const int u = blockIdx.x * blockDim.x + threadIdx.x;
  if (u < 688128) {
    const float* src;
    ushort* dst;
    long i;
    if (u < 393216)      { src = x;  dst = xb;  i = u; }
    else if (u < 614400) { src = wA; dst = wAb; i = u - 393216; }
    else                 { src = wP; dst = wPb; i = u - 614400; }
    const float4* s4 = (const float4*)src;
    float4 a = s4[i * 2], b = s4[i * 2 + 1];
    uint4 o;
    o.x = (uint)f2b(a.x) | ((uint)f2b(a.y) << 16);
    o.y = (uint)f2b(a.z) | ((uint)f2b(a.w) << 16);
    o.z = (uint)f2b(b.x) | ((uint)f2b(b.y) << 16);
    o.w = (uint)f2b(b.z) | ((uint)f2b(b.w) << 16);
    *(uint4*)(dst + i * 8) = o;
  } else if (u < 704512) {
    const int base = (u - 688128) * 8;   // i = t*32 + d
    const int t = base >> 5;
#pragma unroll
    for (int j = 0; j < 8; ++j) {
      const int d = (base + j) & 31;
      float theta = EXP2F((float)d * (-13.28771238f / 32.0f));  // 10000^(-d/32)
      float a = (float)t * theta;
      cosT[base + j] = cosf(a);
      sinT[base + j] = sinf(a);
    }
  }
}

// ---------------- GEMM1 + fused RoPE/reorder epilogue (BK=32 dbuf: LDS 32KB -> 4 blk/CU) ----------------
__global__ __launch_bounds__(256, 4) void gemm_qkv(const ushort* __restrict__ A,
                                                   const ushort* __restrict__ B,
                                                   const float* __restrict__ cosT,
                                                   const float* __restrict__ sinT,
                                                   ushort* __restrict__ Q,
                                                   ushort* __restrict__ Kb,
                                                   ushort* __restrict__ Vt) {
  __shared__ ushort As[2][4096];   // [128 rows][32]
  __shared__ ushort Bs[2][4096];
  const int wg = (blockIdx.x & 7) * 72 + (blockIdx.x >> 3);
  const int bx = wg % 18;
  const int by = wg / 18;
  const int t = threadIdx.x;
  const int w = t >> 6, l = t & 63;
  const int lo = l & 15, hi = l >> 4;
  const int wr = w >> 1, wc = w & 1;
  const long arow = (long)by * 128;
  const long brow = (long)bx * 128;
  const int K = 768;
  f32x4 acc[4][4] = {};

#define GSTAGE(bufg, k0s)                                                       \
  {                                                                             \
    _Pragma("unroll")                                                           \
    for (int i_ = 0; i_ < 2; ++i_) {                                            \
      int e_ = i_ * 2048 + t * 8;                                               \
      int r_ = e_ >> 5, c_ = e_ & 31;                                           \
      gload_lds16(A + (arow + r_) * (long)K + (k0s) + c_,                       \
                  (char*)&As[bufg][0] + i_ * 4096 + w * 1024);                  \
      gload_lds16(B + (brow + r_) * (long)K + (k0s) + c_,                       \
                  (char*)&Bs[bufg][0] + i_ * 4096 + w * 1024);                  \
    }                                                                           \
  }

  GSTAGE(0, 0);
  __syncthreads();
  int bufg = 0;
  for (int k0 = 0; k0 < K; k0 += 32) {
    if (k0 + 32 < K) GSTAGE(bufg ^ 1, k0 + 32);
    {
      bf16x8 af[4], bfr[4];
      for (int m = 0; m < 4; ++m)
        af[m] = *(const bf16x8*)&As[bufg][(wr * 64 + m * 16 + lo) * 32 + hi * 8];
      for (int n = 0; n < 4; ++n)
        bfr[n] = *(const bf16x8*)&Bs[bufg][(wc * 64 + n * 16 + lo) * 32 + hi * 8];
      for (int m = 0; m < 4; ++m)
        for (int n = 0; n < 4; ++n)
          acc[m][n] = __builtin_amdgcn_mfma_f32_16x16x32_bf16(af[m], bfr[n], acc[m][n], 0, 0, 0);
    }
    __syncthreads();
    bufg ^= 1;
  }
#undef GSTAGE
  // ---- fused epilogue ----
  const int rq = bx / 6;                 // 0=Q, 1=K, 2=V
  const int h  = (bx % 6) * 2 + wc;      // head for this thread's cols
  const long hT = (long)h * T_SEQ;
  if (rq < 2) {
    ushort* dst = (rq == 0) ? Q : Kb;
    const float qsc = (rq == 0) ? 0.125f * 1.44269504f : 1.0f;
#pragma unroll
    for (int m = 0; m < 4; ++m)
#pragma unroll
      for (int r = 0; r < 4; ++r) {
        const long trow = arow + wr * 64 + m * 16 + hi * 4 + r;
        ushort* rowp = dst + (hT + trow) * 64;
        const float* cp = cosT + trow * 32;
        const float* sp = sinT + trow * 32;
#pragma unroll
        for (int n = 0; n < 2; ++n) {
          const int dd = n * 16 + lo;
          const float cs = cp[dd], sn = sp[dd];
          const float a = acc[m][n][r], b = acc[m][n + 2][r];
          rowp[dd]      = f2b((a * cs - b * sn) * qsc);
          rowp[dd + 32] = f2b((a * sn + b * cs) * qsc);
        }
      }
  } else {
#pragma unroll
    for (int m = 0; m < 4; ++m) {
      const long trow0 = arow + wr * 64 + m * 16 + hi * 4;
#pragma unroll
      for (int n = 0; n < 4; ++n) {
        const int d = n * 16 + lo;
        uint2 pk;
        pk.x = (uint)f2b(acc[m][n][0]) | ((uint)f2b(acc[m][n][1]) << 16);
        pk.y = (uint)f2b(acc[m][n][2]) | ((uint)f2b(acc[m][n][3]) << 16);
        *(uint2*)(Vt + ((long)h * 64 + d) * T_SEQ + trow0) = pk;
      }
    }
  }
}

// ---------------- bf16 GEMM, C = A * B^T (fp32 out; out-proj; BK=64 dbuf) ----------------
__global__ __launch_bounds__(256) void gemm_bt(const ushort* __restrict__ A,
                                               const ushort* __restrict__ B,
                                               float* __restrict__ C,
                                               int M, int N, int K) {
  __shared__ ushort As[2][8192];
  __shared__ ushort Bs[2][8192];
  const int nbx = N >> 7;
  const int nwg = (M >> 7) * nbx;
  const int cpx = nwg >> 3;
  const int wg = (blockIdx.x & 7) * cpx + (blockIdx.x >> 3);
  const int bx = wg % nbx;
  const int by = wg / nbx;
  const int t = threadIdx.x;
  const int w = t >> 6, l = t & 63;
  const int lo = l & 15, hi = l >> 4;
  const int wr = w >> 1, wc = w & 1;
  const long arow = (long)by * 128;
  const long brow = (long)bx * 128;
  f32x4 acc[4][4] = {};

#define GSTAGE(bufg, k0s)                                                       \
  {                                                                             \
    _Pragma("unroll")                                                           \
    for (int i_ = 0; i_ < 4; ++i_) {                                            \
      int e_ = i_ * 2048 + t * 8;                                               \
      int r_ = e_ >> 6, c_ = e_ & 63;                                           \
      gload_lds16(A + (arow + r_) * (long)K + (k0s) + c_,                       \
                  (char*)&As[bufg][0] + i_ * 4096 + w * 1024);                  \
      gload_lds16(B + (brow + r_) * (long)K + (k0s) + c_,                       \
                  (char*)&Bs[bufg][0] + i_ * 4096 + w * 1024);                  \
    }                                                                           \
  }

  GSTAGE(0, 0);
  __syncthreads();
  int bufg = 0;
  for (int k0 = 0; k0 < K; k0 += 64) {
    if (k0 + 64 < K) GSTAGE(bufg ^ 1, k0 + 64);
    for (int kk = 0; kk < 2; ++kk) {
      bf16x8 af[4], bfr[4];
      for (int m = 0; m < 4; ++m)
        af[m] = *(const bf16x8*)&As[bufg][(wr * 64 + m * 16 + lo) * 64 + kk * 32 + hi * 8];
      for (int n = 0; n < 4; ++n)
        bfr[n] = *(const bf16x8*)&Bs[bufg][(wc * 64 + n * 16 + lo) * 64 + kk * 32 + hi * 8];
      for (int m = 0; m < 4; ++m)
        for (int n = 0; n < 4; ++n)
          acc[m][n] = __builtin_amdgcn_mfma_f32_16x16x32_bf16(af[m], bfr[n], acc[m][n], 0, 0, 0);
    }
    __syncthreads();
    bufg ^= 1;
  }
#undef GSTAGE
  for (int m = 0; m < 4; ++m) {
    long row0 = arow + wr * 64 + m * 16 + hi * 4;
    for (int n = 0; n < 4; ++n) {
      long col = brow + wc * 64 + n * 16 + lo;
      for (int r = 0; r < 4; ++r)
        C[(row0 + r) * (long)N + col] = acc[m][n][r];
    }
  }
}

// ---------------- flash attention: 8-wave blocks, 512-key chunks, permuted-K, no P-LDS ----------------
// r24 change (ISOLATED): LAZY row-max -- per-lane max feeds the __all defer check directly
// (sufficient bound: row-max = max of 4 per-lane maxes); the 2 cross-lane shfl_xor reduces
// move INSIDE the rarely-taken rescale branch, off the per-iter critical path. m stays
// row-uniform (only updated in-branch from the row-reduced max). o_sum-via-MFMA remains
// permanently dropped (r18/r23 bit-identical failures).
// K rows staged PERMUTED (pi) so each lane's softmax outputs ARE its PV A-fragment.
// Causal key: k0 + (kt>>1)*32 + (kt&1)*4 + hi*8 + r.
__global__ __launch_bounds__(512, 4) void flash_attn(const ushort* __restrict__ Q,
                                                     const ushort* __restrict__ Kb,
                                                     const ushort* __restrict__ Vt,
                                                     char* __restrict__ part) {
  const int n    = blockIdx.x;
  const int slot = n >> 3;
  const int u    = slot / 72;                       // unit slot within XCD (0..2)
  int b          = slot - u * 72;                   // block index within unit
  const int unit = (n & 7) * 3 + u;                 // 0..23
  const int h    = unit >> 1;
  const int par  = unit & 1;
  const int top  = par ? 31 : 30;
  int qb = 0, cc = 0;
#pragma unroll 1
  for (int j = 0; j < 16; ++j) {                    // decode b -> (qb, cc), longest-qb first
    int q = top - 2 * j;
    int nc = (q >> 2) + 1;
    if (b < nc) { qb = q; cc = b; break; }
    b -= nc;
  }
  const int kstart  = cc << 9;
  const int blk_lim = qb * 128 + 128;
  const int kend = (kstart + 512 < blk_lim) ? kstart + 512 : blk_lim;

  __shared__ ushort Ks[2][4096];   // [64 rows][64 bf16], rows key-permuted, chunks XOR-swizzled
  __shared__ ushort Vs[2][4096];

  const int t = threadIdx.x;
  const int w = t >> 6, l = t & 63;
  const int lo = l & 15, hi = l >> 4, lo7 = l & 7;
  const int qrow0 = qb * 128 + w * 16;
  const int qlim  = qrow0 + 16;
  const int qabs  = qrow0 + lo;
  const long hT   = (long)h * T_SEQ;
  const long hT64 = (long)h * 64;

  const int srow8 = l >> 3;               // 0..7: row within this wave's 8-row group
  const int row_w = w * 8 + srow8;        // 0..63: LDS tile row this lane stages
  const int prow  = ((row_w >> 5) & 1) * 32 + ((row_w >> 2) & 3) * 8 +
                    ((row_w >> 4) & 1) * 4 + (row_w & 3);   // pi(row_w): source K key
  const int schk  = (l & 7) ^ srow8;      // inverse-swizzled source 16B-chunk

  bf16x8 qf0, qf1;
  {
    const ushort* qp = Q + (hT + qrow0 + lo) * 64 + hi * 8;
    qf0 = *(const bf16x8*)qp;
    qf1 = *(const bf16x8*)(qp + 32);
  }
  f32x4 o[4] = {};
  float m = -1e30f, lsum = 0.0f;

#define STAGE(buf, k0s)                                                         \
  {                                                                             \
    gload_lds16(Kb + (hT + (k0s) + prow) * 64 + schk * 8,                       \
                (char*)&Ks[buf][0] + w * 1024);                                 \
    gload_lds16(Vt + (hT64 + row_w) * T_SEQ + (k0s) + schk * 8,                 \
                (char*)&Vs[buf][0] + w * 1024);                                 \
  }

  STAGE(0, kstart);
  __syncthreads();
  int buf = 0;

  for (int k0 = kstart; k0 < kend; k0 += 64) {
    if (k0 + 64 < kend) STAGE(buf ^ 1, k0 + 64);
    if (k0 < qlim) {
      const ushort* kt_ = &Ks[buf][0];
      const ushort* vt_ = &Vs[buf][0];
      // --- S^T = K . Q^T from swizzled LDS (rows key-permuted) ---
      f32x4 s[4];
      __builtin_amdgcn_s_setprio(1);
#pragma unroll
      for (int kt = 0; kt < 4; ++kt) {
        int rr = kt * 16 + lo;
        bf16x8 ka = *(const bf16x8*)(kt_ + rr * 64 + ((hi ^ lo7) * 8));
        bf16x8 kc = *(const bf16x8*)(kt_ + rr * 64 + (((4 + hi) ^ lo7) * 8));
        f32x4 a = {};
        a = __builtin_amdgcn_mfma_f32_16x16x32_bf16(ka, qf0, a, 0, 0, 0);
        a = __builtin_amdgcn_mfma_f32_16x16x32_bf16(kc, qf1, a, 0, 0, 0);
        s[kt] = a;
      }
      __builtin_amdgcn_s_setprio(0);
      // --- V fragments early (latency overlaps softmax) ---
      bf16x8 vf[8];
#pragma unroll
      for (int dt = 0; dt < 4; ++dt)
#pragma unroll
        for (int cv = 0; cv < 2; ++cv) {
          int rr = dt * 16 + lo;
          vf[dt * 2 + cv] = *(const bf16x8*)(vt_ + rr * 64 + (((cv * 4 + hi) ^ lo7) * 8));
        }
      // --- causal mask (diagonal tiles only); key honors the row permutation ---
      if (k0 + 64 > qrow0) {
#pragma unroll
        for (int kt = 0; kt < 4; ++kt) {
          const int bkt = (kt >> 1) * 32 + (kt & 1) * 4;
#pragma unroll
          for (int r = 0; r < 4; ++r) {
            int key = k0 + bkt + hi * 8 + r;
            if (key > qabs) s[kt][r] = -1e30f;
          }
        }
      }
      // --- per-lane max (max3 tree); cross-lane reduce deferred into the branch ---
      float m1 = max3f(s[0][0], s[0][1], s[0][2]);
      float m2 = max3f(s[0][3], s[1][0], s[1][1]);
      float m3 = max3f(s[1][2], s[1][3], s[2][0]);
      float m4 = max3f(s[2][1], s[2][2], s[2][3]);
      float m5 = max3f(s[3][0], s[3][1], s[3][2]);
      float mt = max3f(max3f(m1, m2, m3), max3f(m4, m5, s[3][3]), -1e30f);
      // --- defer-max (THR=8, log2 domain): per-lane max bounds the row max,
      //     so __all on it is a sufficient skip condition; shfls only on rescale ---
      if (!__all(mt - m <= 8.0f)) {
        mt = fmaxf(mt, __shfl_xor(mt, 16));
        mt = fmaxf(mt, __shfl_xor(mt, 32));
        float mn = fmaxf(m, mt);
        float alpha = EXP2F(m - mn);
        m = mn;
        lsum *= alpha;
#pragma unroll
        for (int r = 0; r < 4; ++r) {
          float ar = __shfl(alpha, hi * 4 + r);
#pragma unroll
          for (int dt = 0; dt < 4; ++dt) o[dt][r] *= ar;
        }
      }
      // --- exp2 + per-lane sum + pack P via v_cvt_pk_bf16_f32 ---
      uint us[8];
#pragma unroll
      for (int kt = 0; kt < 4; ++kt) {
        float p0 = EXP2F(s[kt][0] - m);
        float p1 = EXP2F(s[kt][1] - m);
        float p2 = EXP2F(s[kt][2] - m);
        float p3 = EXP2F(s[kt][3] - m);
        lsum += (p0 + p1) + (p2 + p3);
        us[kt * 2]     = cvt_pk_bf16(p0, p1);
        us[kt * 2 + 1] = cvt_pk_bf16(p2, p3);
      }
      // --- PV: A-fragment is a pure register reassembly ---
      __builtin_amdgcn_s_setprio(1);
#pragma unroll
      for (int cv = 0; cv < 2; ++cv) {
        union { uint4 q; bf16x8 v; } pc;
        pc.q.x = us[cv * 4 + 0];
        pc.q.y = us[cv * 4 + 1];
        pc.q.z = us[cv * 4 + 2];
        pc.q.w = us[cv * 4 + 3];
#pragma unroll
        for (int dt = 0; dt < 4; ++dt)
          o[dt] = __builtin_amdgcn_mfma_f32_16x16x32_bf16(pc.v, vf[dt * 2 + cv], o[dt], 0, 0, 0);
      }
      __builtin_amdgcn_s_setprio(0);
    }
    __syncthreads();
    buf ^= 1;
  }
#undef STAGE

  // --- write partial (unnormalized); compact prefix-indexed slot ---
  if (kstart < qlim) {
    lsum += __shfl_xor(lsum, 16);
    lsum += __shfl_xor(lsum, 32);
    const int g  = qb >> 2;
    const int rr = 8 * (qb & 3) + w;
    const long slotp = (long)h * 1152 + 16 * g * (g + 1) + rr * (g + 1) + cc;
    char* pb = part + slotp * 2176;
    ushort* po = (ushort*)pb;
#pragma unroll
    for (int dt = 0; dt < 4; ++dt)
#pragma unroll
      for (int r = 0; r < 4; ++r)
        po[(hi * 4 + r) * 64 + dt * 16 + lo] = f2b(o[dt][r]);
    if (hi == 0) {
      ((float*)(pb + 2048))[lo] = m;
      ((float*)(pb + 2112))[lo] = lsum;
    }
  }
}

// ---------------- split-K combine: 256 threads, 4 qg/block, 16B loads (2 rows x 8 cols/thread) ----------------
__global__ __launch_bounds__(256) void flash_combine(const char* __restrict__ part,
                                                     ushort* __restrict__ Y) {
  const int h  = blockIdx.y;
  const int qg = blockIdx.x * 4 + (threadIdx.x >> 6);  // grid.x = 64; 4 qg never straddle a g-boundary
  const int tl = threadIdx.x & 63;
  const int dg = tl & 7;          // cols dg*8 .. dg*8+7
  const int rg = tl >> 3;         // rows rg*2, rg*2+1
  const int qrow0 = qg * 16;
  const int g = qg >> 5, rr = qg & 31;
  const int nch = g + 1;
  const char* ub = part + ((long)h * 1152 + 16 * g * (g + 1) + (long)rr * (g + 1)) * 2176;
  float Mg[2] = {-1e30f, -1e30f};
  for (int cc = 0; cc < nch; ++cc) {
    const float* mp = (const float*)(ub + cc * 2176 + 2048);
    Mg[0] = fmaxf(Mg[0], mp[rg * 2]);
    Mg[1] = fmaxf(Mg[1], mp[rg * 2 + 1]);
  }
  float acc[2][8] = {};
  float lg[2] = {};
  for (int cc = 0; cc < nch; ++cc) {
    const ushort* op = (const ushort*)(ub + cc * 2176);
    const float* mp = (const float*)(ub + cc * 2176 + 2048);
    const float* lp = (const float*)(ub + cc * 2176 + 2112);
#pragma unroll
    for (int r = 0; r < 2; ++r) {
      const int ra = rg * 2 + r;
      const float wgt = EXP2F(mp[ra] - Mg[r]);
      uint4 v = *(const uint4*)(op + ra * 64 + dg * 8);
      acc[r][0] += wgt * b2f_lo(v.x);
      acc[r][1] += wgt * b2f_hi(v.x);
      acc[r][2] += wgt * b2f_lo(v.y);
      acc[r][3] += wgt * b2f_hi(v.y);
      acc[r][4] += wgt * b2f_lo(v.z);
      acc[r][5] += wgt * b2f_hi(v.z);
      acc[r][6] += wgt * b2f_lo(v.w);
      acc[r][7] += wgt * b2f_hi(v.w);
      lg[r] += wgt * lp[ra];
    }
  }
#pragma unroll
  for (int r = 0; r < 2; ++r) {
    const float inv = 1.0f / lg[r];
    uint4 wv;
    wv.x = cvt_pk_bf16(acc[r][0] * inv, acc[r][1] * inv);
    wv.y = cvt_pk_bf16(acc[r][2] * inv, acc[r][3] * inv);
    wv.z = cvt_pk_bf16(acc[r][4] * inv, acc[r][5] * inv);
    wv.w = cvt_pk_bf16(acc[r][6] * inv, acc[r][7] * inv);
    *(uint4*)(Y + (long)(qrow0 + rg * 2 + r) * 768 + h * 64 + dg * 8) = wv;
  }
}

extern "C" void kernel_launch(void* const* d_in, const int* in_sizes, int n_in,
                              void* d_out, int out_size, void* d_ws, size_t ws_size,
                              hipStream_t stream) {
  const float* x      = (const float*)d_in[0];
  const float* w_attn = (const float*)d_in[1];
  const float* w_proj = (const float*)d_in[2];
  float* out = (float*)d_out;
  char* ws = (char*)d_ws;

  ushort* xb   = (ushort*)(ws);                 // 4096*768
  ushort* wAb  = (ushort*)(ws + 6291456);       // 2304*768
  ushort* wPb  = (ushort*)(ws + 9830400);       // 768*768
  float*  cosT = (float*)(ws + 11010048);       // 4096*32
  float*  sinT = (float*)(ws + 11534336);
  char*   partR = (ws + 12058624);              // flash split-K partials (compact, 30.1MB)
  ushort* Qb   = (ushort*)(ws + 49807360);      // [12][4096][64]
  ushort* Kbb  = (ushort*)(ws + 56098816);
  ushort* Vt   = (ushort*)(ws + 62390272);      // [12][64][4096]
  ushort* Yb   = (ushort*)(ws + 68681728);      // [4096][768]

  prep_all<<<2752, 256, 0, stream>>>(x, w_attn, w_proj, xb, wAb, wPb, cosT, sinT);
  gemm_qkv<<<576, 256, 0, stream>>>(xb, wAb, cosT, sinT, Qb, Kbb, Vt);
  flash_attn<<<1728, 512, 0, stream>>>(Qb, Kbb, Vt, partR);
  flash_combine<<<dim3(64, NH), 256, 0, stream>>>(partR, Yb);
  gemm_bt<<<192, 256, 0, stream>>>(Yb, wPb, out, 4096, 768, 768);
}